// Round 1
// baseline (1290.331 us; speedup 1.0000x reference)
//
#include <hip/hip_runtime.h>
#include <hip/hip_bf16.h>
#include <math.h>

#define N_NODES 50000
#define N_EDGES 1600000
#define DIN     2000
#define HDIM    128
#define ZDIM    32

// ---------------- workspace layout (bytes) ----------------
// bufA / bufB / bufC : N*128 f32 each (25.6 MB)
// csr_src (E int), csr_w (E f32), cnt, cnt2, offs (N+1), dinv, bn accumulators
#define OFF_BUFA      0UL
#define OFF_BUFB      25600000UL
#define OFF_BUFC      51200000UL
#define OFF_CSRSRC    76800000UL
#define OFF_CSRW      83200000UL
#define OFF_CNT       89600000UL
#define OFF_CNT2      89800000UL
#define OFF_OFFS      90000000UL
#define OFF_DINV      90200064UL
#define OFF_SUMSA     90400064UL
#define OFF_SUMSB     90401088UL
#define OFF_PARAMSA   90402112UL
#define OFF_PARAMSB   90403136UL

__global__ void k_zero(int* cnt, int* cnt2, float* sumsA, float* sumsB) {
    int i = blockIdx.x * blockDim.x + threadIdx.x;
    if (i < N_NODES) { cnt[i] = 0; cnt2[i] = 0; }
    if (i < 256)     { sumsA[i] = 0.f; sumsB[i] = 0.f; }
}

__global__ void k_count(const int* __restrict__ dst, int* __restrict__ cnt) {
    int e = blockIdx.x * blockDim.x + threadIdx.x;
    if (e < N_EDGES) atomicAdd(&cnt[dst[e]], 1);
}

// single-block exclusive scan over cnt -> offs; also dinv = rsqrt(cnt+1)
__global__ void k_scan(const int* __restrict__ cnt, int* __restrict__ offs,
                       float* __restrict__ dinv) {
    __shared__ int sums[1024];
    const int CH = (N_NODES + 1023) / 1024;  // 49
    int t = threadIdx.x;
    int base = t * CH;
    int s = 0;
    for (int i = 0; i < CH; ++i) {
        int idx = base + i;
        if (idx < N_NODES) s += cnt[idx];
    }
    sums[t] = s;
    __syncthreads();
    for (int d = 1; d < 1024; d <<= 1) {
        int v = sums[t];
        int add = (t >= d) ? sums[t - d] : 0;
        __syncthreads();
        sums[t] = v + add;
        __syncthreads();
    }
    int run = (t == 0) ? 0 : sums[t - 1];
    for (int i = 0; i < CH; ++i) {
        int idx = base + i;
        if (idx < N_NODES) {
            offs[idx] = run;
            int c = cnt[idx];
            run += c;
            dinv[idx] = rsqrtf((float)(c + 1));  // +1 self loop, deg>0 always
        }
    }
    if (t == 1023) offs[N_NODES] = run;
}

__global__ void k_fill(const int* __restrict__ src, const int* __restrict__ dst,
                       const int* __restrict__ offs, int* __restrict__ cnt2,
                       const float* __restrict__ dinv,
                       int* __restrict__ csr_src, float* __restrict__ csr_w) {
    int e = blockIdx.x * blockDim.x + threadIdx.x;
    if (e >= N_EDGES) return;
    int d = dst[e], s = src[e];
    int p = atomicAdd(&cnt2[d], 1);
    int idx = offs[d] + p;
    csr_src[idx] = s;
    csr_w[idx] = dinv[s];
}

// ---------------- gemm1: x[N,2000] @ W1[2000,128] -> C[N,128] (f32) ----------
__global__ __launch_bounds__(256) void k_gemm1(const float* __restrict__ A,
                                               const float* __restrict__ B,
                                               float* __restrict__ C) {
    __shared__ float As[16][68];   // transposed [k][m], pitch 68 -> 16B aligned rows
    __shared__ float Bs[16][128];
    int tid = threadIdx.x;
    int m0 = blockIdx.x * 64;
    int rg = tid >> 5, cg = tid & 31;
    int r0 = rg * 8, c0 = cg * 4;
    int ar = tid >> 2, akq = tid & 3;
    bool arok = (m0 + ar) < N_NODES;
    int bk = tid >> 5, bn = (tid & 31) * 4;
    float acc[8][4] = {};
    for (int k0 = 0; k0 < DIN; k0 += 16) {
        float4 av = make_float4(0.f, 0.f, 0.f, 0.f);
        if (arok) av = *(const float4*)(A + (m0 + ar) * DIN + k0 + akq * 4);
        As[akq * 4 + 0][ar] = av.x;
        As[akq * 4 + 1][ar] = av.y;
        As[akq * 4 + 2][ar] = av.z;
        As[akq * 4 + 3][ar] = av.w;
        *(float4*)&Bs[bk][bn]     = *(const float4*)(B + (k0 + bk) * HDIM + bn);
        *(float4*)&Bs[bk + 8][bn] = *(const float4*)(B + (k0 + bk + 8) * HDIM + bn);
        __syncthreads();
#pragma unroll
        for (int k = 0; k < 16; ++k) {
            float a_[8], b_[4];
            *(float4*)&a_[0] = *(const float4*)&As[k][r0];
            *(float4*)&a_[4] = *(const float4*)&As[k][r0 + 4];
            *(float4*)&b_[0] = *(const float4*)&Bs[k][c0];
#pragma unroll
            for (int i = 0; i < 8; ++i)
#pragma unroll
                for (int j = 0; j < 4; ++j) acc[i][j] += a_[i] * b_[j];
        }
        __syncthreads();
    }
#pragma unroll
    for (int i = 0; i < 8; ++i) {
        int r = m0 + r0 + i;
        if (r < N_NODES) *(float4*)&C[r * HDIM + c0] = *(float4*)&acc[i][0];
    }
}

// ---------------- aggregation: out[d] = dinv[d]*(sum_e w_e*h[src_e] + dinv[d]*h[d])
template <int C>
__global__ void k_agg(const float* __restrict__ h, const int* __restrict__ offs,
                      const int* __restrict__ csr_src, const float* __restrict__ csr_w,
                      const float* __restrict__ dinv, float* __restrict__ out) {
    int row = blockIdx.x;
    int c = threadIdx.x;
    float di = dinv[row];
    float acc = di * h[row * C + c];
    int p1 = offs[row + 1];
    for (int p = offs[row]; p < p1; ++p) {
        int s = csr_src[p];
        float w = csr_w[p];
        acc += w * h[s * C + c];
    }
    out[row * C + c] = di * acc;
}

__global__ void k_bnstats(const float* __restrict__ h, float* __restrict__ sums) {
    int c = threadIdx.x;  // 128
    float s = 0.f, q = 0.f;
    for (int r = blockIdx.x; r < N_NODES; r += gridDim.x) {
        float v = h[r * HDIM + c];
        s += v;
        q += v * v;
    }
    atomicAdd(&sums[c], s);
    atomicAdd(&sums[128 + c], q);
}

__global__ void k_bnfin(const float* __restrict__ sums, const float* __restrict__ g,
                        const float* __restrict__ be, float* __restrict__ params) {
    int c = threadIdx.x;  // 128
    float mean = sums[c] * (1.f / N_NODES);
    float var = sums[128 + c] * (1.f / N_NODES) - mean * mean;
    float rstd = rsqrtf(var + 1e-5f);
    float sc = g[c] * rstd;
    params[c] = sc;
    params[128 + c] = be[c] - mean * sc;
}

// ---------------- gemm2: h0 = relu(bn(aggA)); out = h0 @ W2 -------------------
__global__ __launch_bounds__(256) void k_gemm2(const float* __restrict__ Ain,
                                               const float* __restrict__ W2,
                                               const float* __restrict__ params,
                                               float* __restrict__ h0,
                                               float* __restrict__ Cout) {
    __shared__ float As[32][68];
    __shared__ float Bs[32][128];
    int tid = threadIdx.x;
    int m0 = blockIdx.x * 64;
    int rg = tid >> 5, cg = tid & 31;
    int r0 = rg * 8, c0 = cg * 4;
    int ar = tid >> 2, akq = tid & 3;
    bool arok = (m0 + ar) < N_NODES;
    int bk = tid >> 5, bn = (tid & 31) * 4;
    float acc[8][4] = {};
    for (int k0 = 0; k0 < HDIM; k0 += 32) {
#pragma unroll
        for (int half = 0; half < 2; ++half) {
            int kk = k0 + half * 16 + akq * 4;      // global k
            int kl = half * 16 + akq * 4;           // local k
            float4 av = make_float4(0.f, 0.f, 0.f, 0.f);
            if (arok) av = *(const float4*)(Ain + (m0 + ar) * HDIM + kk);
            float4 sc = *(const float4*)(params + kk);
            float4 sh = *(const float4*)(params + 128 + kk);
            float4 hv;
            hv.x = fmaxf(av.x * sc.x + sh.x, 0.f);
            hv.y = fmaxf(av.y * sc.y + sh.y, 0.f);
            hv.z = fmaxf(av.z * sc.z + sh.z, 0.f);
            hv.w = fmaxf(av.w * sc.w + sh.w, 0.f);
            if (arok) *(float4*)(h0 + (m0 + ar) * HDIM + kk) = hv;
            As[kl + 0][ar] = hv.x;
            As[kl + 1][ar] = hv.y;
            As[kl + 2][ar] = hv.z;
            As[kl + 3][ar] = hv.w;
        }
#pragma unroll
        for (int q = 0; q < 4; ++q)
            *(float4*)&Bs[bk + q * 8][bn] =
                *(const float4*)(W2 + (k0 + bk + q * 8) * HDIM + bn);
        __syncthreads();
#pragma unroll
        for (int k = 0; k < 32; ++k) {
            float a_[8], b_[4];
            *(float4*)&a_[0] = *(const float4*)&As[k][r0];
            *(float4*)&a_[4] = *(const float4*)&As[k][r0 + 4];
            *(float4*)&b_[0] = *(const float4*)&Bs[k][c0];
#pragma unroll
            for (int i = 0; i < 8; ++i)
#pragma unroll
                for (int j = 0; j < 4; ++j) acc[i][j] += a_[i] * b_[j];
        }
        __syncthreads();
    }
#pragma unroll
    for (int i = 0; i < 8; ++i) {
        int r = m0 + r0 + i;
        if (r < N_NODES) *(float4*)&Cout[r * HDIM + c0] = *(float4*)&acc[i][0];
    }
}

// ------- gemm3: h = relu(bn(aggB)) + h0; hmv = h@[Wm|Wv]; t = sigmoid(h@Wt+bt)
__global__ __launch_bounds__(256) void k_gemm3(const float* __restrict__ Ain,
                                               const float* __restrict__ h0,
                                               const float* __restrict__ params,
                                               const float* __restrict__ Wm,
                                               const float* __restrict__ Wv,
                                               const float* __restrict__ Wt,
                                               const float* __restrict__ bt,
                                               float* __restrict__ hmv,
                                               float* __restrict__ t_out) {
    __shared__ float As[128][68];  // transposed [k][r]
    __shared__ float Bs[128][64];
    __shared__ float WtS[128];
    int tid = threadIdx.x;
    int m0 = blockIdx.x * 64;
    int ar = tid >> 2, akq = tid & 3;
    bool arok = (m0 + ar) < N_NODES;
#pragma unroll
    for (int q = 0; q < 8; ++q) {
        int kk = q * 16 + akq * 4;
        float4 av = make_float4(0.f, 0.f, 0.f, 0.f), rv = av;
        if (arok) {
            av = *(const float4*)(Ain + (m0 + ar) * HDIM + kk);
            rv = *(const float4*)(h0 + (m0 + ar) * HDIM + kk);
        }
        float4 sc = *(const float4*)(params + kk);
        float4 sh = *(const float4*)(params + 128 + kk);
        As[kk + 0][ar] = fmaxf(av.x * sc.x + sh.x, 0.f) + rv.x;
        As[kk + 1][ar] = fmaxf(av.y * sc.y + sh.y, 0.f) + rv.y;
        As[kk + 2][ar] = fmaxf(av.z * sc.z + sh.z, 0.f) + rv.z;
        As[kk + 3][ar] = fmaxf(av.w * sc.w + sh.w, 0.f) + rv.w;
    }
#pragma unroll
    for (int q = 0; q < 8; ++q) {
        int k = q * 16 + (tid >> 4);
        int j = (tid & 15) * 4;
        float4 b4 = (j < 32) ? *(const float4*)(Wm + k * ZDIM + j)
                             : *(const float4*)(Wv + k * ZDIM + (j - 32));
        *(float4*)&Bs[k][j] = b4;
    }
    if (tid < 128) WtS[tid] = Wt[tid];
    __syncthreads();
    int rg = tid >> 4, cg = tid & 15;
    int r0 = rg * 4, c0 = cg * 4;
    float acc[4][4] = {};
#pragma unroll 8
    for (int k = 0; k < 128; ++k) {
        float a_[4], b_[4];
        *(float4*)&a_[0] = *(const float4*)&As[k][r0];
        *(float4*)&b_[0] = *(const float4*)&Bs[k][c0];
#pragma unroll
        for (int i = 0; i < 4; ++i)
#pragma unroll
            for (int j = 0; j < 4; ++j) acc[i][j] += a_[i] * b_[j];
    }
#pragma unroll
    for (int i = 0; i < 4; ++i) {
        int r = m0 + r0 + i;
        if (r < N_NODES) *(float4*)&hmv[r * 64 + c0] = *(float4*)&acc[i][0];
    }
    if (tid < 64 && (m0 + tid) < N_NODES) {
        float s = 0.f;
#pragma unroll 8
        for (int k = 0; k < 128; ++k) s += As[k][tid] * WtS[k];
        s += bt[0];
        t_out[m0 + tid] = 1.f / (1.f + expf(-s));
    }
}

// ---------------- final aggregation (64 ch) + VAE epilogue --------------------
__global__ void k_aggfin(const float* __restrict__ hmv, const int* __restrict__ offs,
                         const int* __restrict__ csr_src, const float* __restrict__ csr_w,
                         const float* __restrict__ dinv,
                         const float* __restrict__ bm, const float* __restrict__ bv,
                         const float* __restrict__ eps,
                         float* __restrict__ out_qz, float* __restrict__ out_qm,
                         float* __restrict__ out_qs) {
    __shared__ float qm_s[32], qs_s[32];
    int row = blockIdx.x;
    int c = threadIdx.x;  // 64
    float di = dinv[row];
    float acc = di * hmv[row * 64 + c];
    int p1 = offs[row + 1];
    for (int p = offs[row]; p < p1; ++p) {
        int s = csr_src[p];
        float w = csr_w[p];
        acc += w * hmv[s * 64 + c];
    }
    acc *= di;
    if (c < 32) {
        float qm = acc + bm[c];
        out_qm[row * 32 + c] = qm;
        qm_s[c] = qm;
    } else {
        float qs = acc + bv[c - 32];
        out_qs[row * 32 + (c - 32)] = qs;
        float sp = fmaxf(qs, 0.f) + log1pf(expf(-fabsf(qs)));  // softplus
        qs_s[c - 32] = sp + 1e-6f;
    }
    __syncthreads();
    if (c < 32) out_qz[row * 32 + c] = qm_s[c] + qs_s[c] * eps[row * 32 + c];
}

extern "C" void kernel_launch(void* const* d_in, const int* in_sizes, int n_in,
                              void* d_out, int out_size, void* d_ws, size_t ws_size,
                              hipStream_t stream) {
    (void)in_sizes; (void)n_in; (void)out_size; (void)ws_size;
    const float* x   = (const float*)d_in[0];
    const int*   ei  = (const int*)d_in[1];
    const float* W1  = (const float*)d_in[2];
    const float* W2  = (const float*)d_in[4];
    const float* g1  = (const float*)d_in[6];
    const float* be1 = (const float*)d_in[7];
    const float* g2  = (const float*)d_in[8];
    const float* be2 = (const float*)d_in[9];
    const float* Wm  = (const float*)d_in[10];
    const float* bm  = (const float*)d_in[11];
    const float* Wv  = (const float*)d_in[12];
    const float* bv  = (const float*)d_in[13];
    const float* Wt  = (const float*)d_in[14];
    const float* bt  = (const float*)d_in[15];
    const float* eps = (const float*)d_in[16];
    // b1, b2 cancel through BN mean-subtraction -> unused.

    const int* e_src = ei;            // edge_index[0]
    const int* e_dst = ei + N_EDGES;  // edge_index[1]

    char* ws = (char*)d_ws;
    float* bufA    = (float*)(ws + OFF_BUFA);
    float* bufB    = (float*)(ws + OFF_BUFB);
    float* bufC    = (float*)(ws + OFF_BUFC);
    int*   csr_src = (int*)(ws + OFF_CSRSRC);
    float* csr_w   = (float*)(ws + OFF_CSRW);
    int*   cnt     = (int*)(ws + OFF_CNT);
    int*   cnt2    = (int*)(ws + OFF_CNT2);
    int*   offs    = (int*)(ws + OFF_OFFS);
    float* dinv    = (float*)(ws + OFF_DINV);
    float* sumsA   = (float*)(ws + OFF_SUMSA);
    float* sumsB   = (float*)(ws + OFF_SUMSB);
    float* paramsA = (float*)(ws + OFF_PARAMSA);
    float* paramsB = (float*)(ws + OFF_PARAMSB);

    float* out_qz = (float*)d_out;
    float* out_qm = out_qz + N_NODES * ZDIM;
    float* out_qs = out_qm + N_NODES * ZDIM;
    float* out_t  = out_qs + N_NODES * ZDIM;

    const int MB = (N_NODES + 63) / 64;  // 782 gemm row-blocks

    k_zero<<<(N_NODES + 255) / 256, 256, 0, stream>>>(cnt, cnt2, sumsA, sumsB);
    k_count<<<(N_EDGES + 255) / 256, 256, 0, stream>>>(e_dst, cnt);
    k_scan<<<1, 1024, 0, stream>>>(cnt, offs, dinv);
    k_fill<<<(N_EDGES + 255) / 256, 256, 0, stream>>>(e_src, e_dst, offs, cnt2, dinv,
                                                      csr_src, csr_w);
    // layer 0
    k_gemm1<<<MB, 256, 0, stream>>>(x, W1, bufA);
    k_agg<HDIM><<<N_NODES, HDIM, 0, stream>>>(bufA, offs, csr_src, csr_w, dinv, bufB);
    k_bnstats<<<256, 128, 0, stream>>>(bufB, sumsA);
    k_bnfin<<<1, 128, 0, stream>>>(sumsA, g1, be1, paramsA);
    // layer 1
    k_gemm2<<<MB, 256, 0, stream>>>(bufB, W2, paramsA, bufC, bufA);
    k_agg<HDIM><<<N_NODES, HDIM, 0, stream>>>(bufA, offs, csr_src, csr_w, dinv, bufB);
    k_bnstats<<<256, 128, 0, stream>>>(bufB, sumsB);
    k_bnfin<<<1, 128, 0, stream>>>(sumsB, g2, be2, paramsB);
    // heads
    k_gemm3<<<MB, 256, 0, stream>>>(bufB, bufC, paramsB, Wm, Wv, Wt, bt, bufA, out_t);
    k_aggfin<<<N_NODES, 64, 0, stream>>>(bufA, offs, csr_src, csr_w, dinv, bm, bv, eps,
                                         out_qz, out_qm, out_qs);
}

// Round 2
// 868.559 us; speedup vs baseline: 1.4856x; 1.4856x over previous
//
#include <hip/hip_runtime.h>
#include <hip/hip_bf16.h>
#include <math.h>

#define N_NODES 50000
#define N_EDGES 1600000
#define DIN     2000
#define HDIM    128
#define ZDIM    32

// ---------------- workspace layout (bytes) ----------------
#define OFF_BUFA      0UL
#define OFF_BUFB      25600000UL
#define OFF_BUFC      51200000UL   // first 512KB doubles as W1t (bf16) before gemm2
#define OFF_CSRSRC    76800000UL
#define OFF_CSRW      83200000UL
#define OFF_CNT       89600000UL
#define OFF_CNT2      89800000UL
#define OFF_OFFS      90000000UL
#define OFF_DINV      90200064UL
#define OFF_SUMSA     90400064UL
#define OFF_SUMSB     90401088UL
#define OFF_PARAMSA   90402112UL
#define OFF_PARAMSB   90403136UL

typedef __attribute__((ext_vector_type(8))) short short8;
typedef __attribute__((ext_vector_type(4))) float f32x4;

__device__ inline unsigned short f2bf(float f) {
    unsigned u = __builtin_bit_cast(unsigned, f);
    u += 0x7FFFu + ((u >> 16) & 1u);
    return (unsigned short)(u >> 16);
}

__device__ inline void gload_lds16(const unsigned short* g, unsigned short* l) {
    __builtin_amdgcn_global_load_lds(
        (const __attribute__((address_space(1))) unsigned int*)g,
        (__attribute__((address_space(3))) unsigned int*)l, 16, 0, 0);
}

__device__ inline f32x4 mfma16(short8 a, short8 b, f32x4 c) {
    return __builtin_amdgcn_mfma_f32_16x16x32_bf16(a, b, c, 0, 0, 0);
}

// ---------------- CSR build ----------------
__global__ void k_zero(int* cnt, int* cnt2, float* sumsA, float* sumsB) {
    int i = blockIdx.x * blockDim.x + threadIdx.x;
    if (i < N_NODES) { cnt[i] = 0; cnt2[i] = 0; }
    if (i < 256)     { sumsA[i] = 0.f; sumsB[i] = 0.f; }
}

__global__ void k_count(const int* __restrict__ dst, int* __restrict__ cnt) {
    int e = blockIdx.x * blockDim.x + threadIdx.x;
    if (e < N_EDGES) atomicAdd(&cnt[dst[e]], 1);
}

__global__ void k_scan(const int* __restrict__ cnt, int* __restrict__ offs,
                       float* __restrict__ dinv) {
    __shared__ int sums[1024];
    const int CH = (N_NODES + 1023) / 1024;
    int t = threadIdx.x;
    int base = t * CH;
    int s = 0;
    for (int i = 0; i < CH; ++i) {
        int idx = base + i;
        if (idx < N_NODES) s += cnt[idx];
    }
    sums[t] = s;
    __syncthreads();
    for (int d = 1; d < 1024; d <<= 1) {
        int v = sums[t];
        int add = (t >= d) ? sums[t - d] : 0;
        __syncthreads();
        sums[t] = v + add;
        __syncthreads();
    }
    int run = (t == 0) ? 0 : sums[t - 1];
    for (int i = 0; i < CH; ++i) {
        int idx = base + i;
        if (idx < N_NODES) {
            offs[idx] = run;
            int c = cnt[idx];
            run += c;
            dinv[idx] = rsqrtf((float)(c + 1));
        }
    }
    if (t == 1023) offs[N_NODES] = run;
}

__global__ void k_fill(const int* __restrict__ src, const int* __restrict__ dst,
                       const int* __restrict__ offs, int* __restrict__ cnt2,
                       const float* __restrict__ dinv,
                       int* __restrict__ csr_src, float* __restrict__ csr_w) {
    int e = blockIdx.x * blockDim.x + threadIdx.x;
    if (e >= N_EDGES) return;
    int d = dst[e], s = src[e];
    int p = atomicAdd(&cnt2[d], 1);
    int idx = offs[d] + p;
    csr_src[idx] = s;
    csr_w[idx] = dinv[s];
}

// ---------------- W1 -> bf16 transposed [128][2048], zero pad ----------------
__global__ void k_prep(const float* __restrict__ W1, unsigned short* __restrict__ W1t) {
    int idx = blockIdx.x * 256 + threadIdx.x;   // 128*2048 = 262144
    int n = idx >> 11;
    int k = idx & 2047;
    float v = (k < DIN) ? W1[(size_t)k * HDIM + n] : 0.f;
    W1t[idx] = f2bf(v);
}

// ---------------- gemm1: x[N,2000](f32) @ W1 -> C[N,128], bf16 MFMA ----------
#define G1_BM 64
#define G1_BK 64
__global__ __launch_bounds__(256) void k_gemm1m(const float* __restrict__ A,
                                                const unsigned short* __restrict__ Bt,
                                                float* __restrict__ C) {
    __shared__ __align__(16) unsigned short Abuf[2][G1_BM * G1_BK];
    __shared__ __align__(16) unsigned short Bbuf[2][HDIM * G1_BK];
    const int tid  = threadIdx.x;
    const int lane = tid & 63;
    const int wave = tid >> 6;
    const int m0   = blockIdx.x * G1_BM;
    const int wm   = (wave >> 1) * 32;   // wave m-offset
    const int wn   = (wave & 1) * 64;    // wave n-offset
    const int ar   = tid >> 2;           // staging row 0..63
    const int acp  = tid & 3;            // staging chunk-pair

    f32x4 acc[2][4];
#pragma unroll
    for (int i = 0; i < 2; ++i)
#pragma unroll
        for (int j = 0; j < 4; ++j) acc[i][j] = (f32x4)0.f;

    float areg[16];

    auto stageA = [&](int k0) {
        const int g = m0 + ar;
        const int kk = k0 + acp * 16;
        if (g < N_NODES && kk < DIN) {
#pragma unroll
            for (int q = 0; q < 4; ++q)
                *(float4*)&areg[q * 4] = *(const float4*)(A + (size_t)g * DIN + kk + q * 4);
        } else {
#pragma unroll
            for (int q = 0; q < 16; ++q) areg[q] = 0.f;
        }
    };

    auto writeA = [&](int c) {
        unsigned short u[16];
#pragma unroll
        for (int q = 0; q < 16; ++q) u[q] = f2bf(areg[q]);
#pragma unroll
        for (int q = 0; q < 2; ++q) {
            int chunk = acp * 2 + q;                  // data chunk (8 bf16)
            int pos = chunk ^ (ar & 7);               // T2 XOR swizzle
            *(uint4*)&Abuf[c][ar * G1_BK + pos * 8] = *(const uint4*)&u[q * 8];
        }
    };

    auto issueB = [&](int k0, int c) {
#pragma unroll
        for (int q = 0; q < 4; ++q) {
            int nbase = wave * 32 + q * 8;            // 8 n-rows per wave-issue
            int n = nbase + (lane >> 3);
            int pos = lane & 7;                       // LDS chunk position
            int ksrc = k0 + ((pos ^ (n & 7)) * 8);    // pre-swizzled source
            gload_lds16(Bt + (size_t)n * 2048 + ksrc, &Bbuf[c][nbase * G1_BK]);
        }
    };

    auto compute = [&](int c) {
        const int rl = lane & 15;
        const int kg = lane >> 4;                     // 0..3 (8-k group)
#pragma unroll
        for (int ks = 0; ks < 2; ++ks) {
            short8 a[2], b[4];
#pragma unroll
            for (int i = 0; i < 2; ++i) {
                int r = wm + i * 16 + rl;
                int pos = (kg + ks * 4) ^ (r & 7);
                a[i] = *(const short8*)&Abuf[c][r * G1_BK + pos * 8];
            }
#pragma unroll
            for (int j = 0; j < 4; ++j) {
                int n = wn + j * 16 + rl;
                int pos = (kg + ks * 4) ^ (n & 7);
                b[j] = *(const short8*)&Bbuf[c][n * G1_BK + pos * 8];
            }
#pragma unroll
            for (int i = 0; i < 2; ++i)
#pragma unroll
                for (int j = 0; j < 4; ++j)
                    acc[i][j] = mfma16(a[i], b[j], acc[i][j]);
        }
    };

    const int NT = 32;                                // 2000 -> 32 steps of 64 (padded)
    stageA(0);
    issueB(0, 0);
#pragma unroll 1
    for (int t = 0; t < NT; ++t) {
        const int c = t & 1;
        writeA(c);
        __syncthreads();                              // A(t) visible, B(t) landed
        if (t + 1 < NT) { stageA((t + 1) * G1_BK); issueB((t + 1) * G1_BK, c ^ 1); }
        compute(c);
        __syncthreads();
    }
#pragma unroll
    for (int i = 0; i < 2; ++i) {
        int rb = m0 + wm + i * 16 + (lane >> 4) * 4;
#pragma unroll
        for (int j = 0; j < 4; ++j) {
            int col = wn + j * 16 + (lane & 15);
#pragma unroll
            for (int r = 0; r < 4; ++r)
                if (rb + r < N_NODES) C[(size_t)(rb + r) * HDIM + col] = acc[i][j][r];
        }
    }
}

// ---------------- aggregation (128 ch, float4) -------------------------------
__global__ __launch_bounds__(256) void k_agg128(const float* __restrict__ h,
        const int* __restrict__ offs, const int* __restrict__ csr_src,
        const float* __restrict__ csr_w, const float* __restrict__ dinv,
        float* __restrict__ out) {
    const int row = blockIdx.x * 8 + (threadIdx.x >> 5);
    const int c = (threadIdx.x & 31) * 4;
    const float di = dinv[row];
    float4 hv = *(const float4*)(h + (size_t)row * HDIM + c);
    float ax = di * hv.x, ay = di * hv.y, az = di * hv.z, aw = di * hv.w;
    const int p1 = offs[row + 1];
#pragma unroll 4
    for (int p = offs[row]; p < p1; ++p) {
        int s = csr_src[p];
        float w = csr_w[p];
        float4 v = *(const float4*)(h + (size_t)s * HDIM + c);
        ax += w * v.x; ay += w * v.y; az += w * v.z; aw += w * v.w;
    }
    float4 o;
    o.x = di * ax; o.y = di * ay; o.z = di * az; o.w = di * aw;
    *(float4*)(out + (size_t)row * HDIM + c) = o;
}

__global__ void k_bnstats(const float* __restrict__ h, float* __restrict__ sums) {
    int c = threadIdx.x;  // 128
    float s = 0.f, q = 0.f;
    for (int r = blockIdx.x; r < N_NODES; r += gridDim.x) {
        float v = h[r * HDIM + c];
        s += v;
        q += v * v;
    }
    atomicAdd(&sums[c], s);
    atomicAdd(&sums[128 + c], q);
}

__global__ void k_bnfin(const float* __restrict__ sums, const float* __restrict__ g,
                        const float* __restrict__ be, float* __restrict__ params) {
    int c = threadIdx.x;  // 128
    float mean = sums[c] * (1.f / N_NODES);
    float var = sums[128 + c] * (1.f / N_NODES) - mean * mean;
    float rstd = rsqrtf(var + 1e-5f);
    float sc = g[c] * rstd;
    params[c] = sc;
    params[128 + c] = be[c] - mean * sc;
}

// ---------------- gemm2: h0 = relu(bn(aggA)); out = h0 @ W2 ------------------
__global__ __launch_bounds__(256) void k_gemm2(const float* __restrict__ Ain,
                                               const float* __restrict__ W2,
                                               const float* __restrict__ params,
                                               float* __restrict__ h0,
                                               float* __restrict__ Cout) {
    __shared__ float As[32][68];
    __shared__ float Bs[32][128];
    int tid = threadIdx.x;
    int m0 = blockIdx.x * 64;
    int rg = tid >> 5, cg = tid & 31;
    int r0 = rg * 8, c0 = cg * 4;
    int ar = tid >> 2, akq = tid & 3;
    bool arok = (m0 + ar) < N_NODES;
    int bk = tid >> 5, bn = (tid & 31) * 4;
    float acc[8][4] = {};
    for (int k0 = 0; k0 < HDIM; k0 += 32) {
#pragma unroll
        for (int half = 0; half < 2; ++half) {
            int kk = k0 + half * 16 + akq * 4;
            int kl = half * 16 + akq * 4;
            float4 av = make_float4(0.f, 0.f, 0.f, 0.f);
            if (arok) av = *(const float4*)(Ain + (m0 + ar) * HDIM + kk);
            float4 sc = *(const float4*)(params + kk);
            float4 sh = *(const float4*)(params + 128 + kk);
            float4 hv;
            hv.x = fmaxf(av.x * sc.x + sh.x, 0.f);
            hv.y = fmaxf(av.y * sc.y + sh.y, 0.f);
            hv.z = fmaxf(av.z * sc.z + sh.z, 0.f);
            hv.w = fmaxf(av.w * sc.w + sh.w, 0.f);
            if (arok) *(float4*)(h0 + (m0 + ar) * HDIM + kk) = hv;
            As[kl + 0][ar] = hv.x;
            As[kl + 1][ar] = hv.y;
            As[kl + 2][ar] = hv.z;
            As[kl + 3][ar] = hv.w;
        }
#pragma unroll
        for (int q = 0; q < 4; ++q)
            *(float4*)&Bs[bk + q * 8][bn] =
                *(const float4*)(W2 + (k0 + bk + q * 8) * HDIM + bn);
        __syncthreads();
#pragma unroll
        for (int k = 0; k < 32; ++k) {
            float a_[8], b_[4];
            *(float4*)&a_[0] = *(const float4*)&As[k][r0];
            *(float4*)&a_[4] = *(const float4*)&As[k][r0 + 4];
            *(float4*)&b_[0] = *(const float4*)&Bs[k][c0];
#pragma unroll
            for (int i = 0; i < 8; ++i)
#pragma unroll
                for (int j = 0; j < 4; ++j) acc[i][j] += a_[i] * b_[j];
        }
        __syncthreads();
    }
#pragma unroll
    for (int i = 0; i < 8; ++i) {
        int r = m0 + r0 + i;
        if (r < N_NODES) *(float4*)&Cout[r * HDIM + c0] = *(float4*)&acc[i][0];
    }
}

// ------- gemm3: h = relu(bn(aggB)) + h0; hmv = h@[Wm|Wv]; t = sigmoid(h@Wt+bt)
__global__ __launch_bounds__(256) void k_gemm3(const float* __restrict__ Ain,
                                               const float* __restrict__ h0,
                                               const float* __restrict__ params,
                                               const float* __restrict__ Wm,
                                               const float* __restrict__ Wv,
                                               const float* __restrict__ Wt,
                                               const float* __restrict__ bt,
                                               float* __restrict__ hmv,
                                               float* __restrict__ t_out) {
    __shared__ float As[128][68];
    __shared__ float Bs[128][64];
    __shared__ float WtS[128];
    int tid = threadIdx.x;
    int m0 = blockIdx.x * 64;
    int ar = tid >> 2, akq = tid & 3;
    bool arok = (m0 + ar) < N_NODES;
#pragma unroll
    for (int q = 0; q < 8; ++q) {
        int kk = q * 16 + akq * 4;
        float4 av = make_float4(0.f, 0.f, 0.f, 0.f), rv = av;
        if (arok) {
            av = *(const float4*)(Ain + (m0 + ar) * HDIM + kk);
            rv = *(const float4*)(h0 + (m0 + ar) * HDIM + kk);
        }
        float4 sc = *(const float4*)(params + kk);
        float4 sh = *(const float4*)(params + 128 + kk);
        As[kk + 0][ar] = fmaxf(av.x * sc.x + sh.x, 0.f) + rv.x;
        As[kk + 1][ar] = fmaxf(av.y * sc.y + sh.y, 0.f) + rv.y;
        As[kk + 2][ar] = fmaxf(av.z * sc.z + sh.z, 0.f) + rv.z;
        As[kk + 3][ar] = fmaxf(av.w * sc.w + sh.w, 0.f) + rv.w;
    }
#pragma unroll
    for (int q = 0; q < 8; ++q) {
        int k = q * 16 + (tid >> 4);
        int j = (tid & 15) * 4;
        float4 b4 = (j < 32) ? *(const float4*)(Wm + k * ZDIM + j)
                             : *(const float4*)(Wv + k * ZDIM + (j - 32));
        *(float4*)&Bs[k][j] = b4;
    }
    if (tid < 128) WtS[tid] = Wt[tid];
    __syncthreads();
    int rg = tid >> 4, cg = tid & 15;
    int r0 = rg * 4, c0 = cg * 4;
    float acc[4][4] = {};
#pragma unroll 8
    for (int k = 0; k < 128; ++k) {
        float a_[4], b_[4];
        *(float4*)&a_[0] = *(const float4*)&As[k][r0];
        *(float4*)&b_[0] = *(const float4*)&Bs[k][c0];
#pragma unroll
        for (int i = 0; i < 4; ++i)
#pragma unroll
            for (int j = 0; j < 4; ++j) acc[i][j] += a_[i] * b_[j];
    }
#pragma unroll
    for (int i = 0; i < 4; ++i) {
        int r = m0 + r0 + i;
        if (r < N_NODES) *(float4*)&hmv[r * 64 + c0] = *(float4*)&acc[i][0];
    }
    if (tid < 64 && (m0 + tid) < N_NODES) {
        float s = 0.f;
#pragma unroll 8
        for (int k = 0; k < 128; ++k) s += As[k][tid] * WtS[k];
        s += bt[0];
        t_out[m0 + tid] = 1.f / (1.f + expf(-s));
    }
}

// ---------------- final aggregation (64 ch, float4) + VAE epilogue -----------
__global__ __launch_bounds__(256) void k_aggfin2(const float* __restrict__ hmv,
        const int* __restrict__ offs, const int* __restrict__ csr_src,
        const float* __restrict__ csr_w, const float* __restrict__ dinv,
        const float* __restrict__ bm, const float* __restrict__ bv,
        const float* __restrict__ eps,
        float* __restrict__ out_qz, float* __restrict__ out_qm,
        float* __restrict__ out_qs) {
    const int row = blockIdx.x * 16 + (threadIdx.x >> 4);
    const int cq = threadIdx.x & 15;
    const int c = cq * 4;
    const float di = dinv[row];
    float4 hv = *(const float4*)(hmv + (size_t)row * 64 + c);
    float ax = di * hv.x, ay = di * hv.y, az = di * hv.z, aw = di * hv.w;
    const int p1 = offs[row + 1];
#pragma unroll 4
    for (int p = offs[row]; p < p1; ++p) {
        int s = csr_src[p];
        float w = csr_w[p];
        float4 v = *(const float4*)(hmv + (size_t)s * 64 + c);
        ax += w * v.x; ay += w * v.y; az += w * v.z; aw += w * v.w;
    }
    float qv[4];
    const bool lo = cq < 8;
    if (lo) {
        qv[0] = di * ax + bm[c + 0]; qv[1] = di * ay + bm[c + 1];
        qv[2] = di * az + bm[c + 2]; qv[3] = di * aw + bm[c + 3];
    } else {
        qv[0] = di * ax + bv[c - 32 + 0]; qv[1] = di * ay + bv[c - 32 + 1];
        qv[2] = di * az + bv[c - 32 + 2]; qv[3] = di * aw + bv[c - 32 + 3];
    }
    float sp[4] = {0.f, 0.f, 0.f, 0.f};
    if (!lo) {
#pragma unroll
        for (int k = 0; k < 4; ++k)
            sp[k] = fmaxf(qv[k], 0.f) + log1pf(expf(-fabsf(qv[k]))) + 1e-6f;
    }
    float spx[4];
#pragma unroll
    for (int k = 0; k < 4; ++k) spx[k] = __shfl_xor(sp[k], 8);
    if (lo) {
        *(float4*)(out_qm + (size_t)row * 32 + c) = make_float4(qv[0], qv[1], qv[2], qv[3]);
        float4 e = *(const float4*)(eps + (size_t)row * 32 + c);
        float4 qz;
        qz.x = qv[0] + spx[0] * e.x; qz.y = qv[1] + spx[1] * e.y;
        qz.z = qv[2] + spx[2] * e.z; qz.w = qv[3] + spx[3] * e.w;
        *(float4*)(out_qz + (size_t)row * 32 + c) = qz;
    } else {
        *(float4*)(out_qs + (size_t)row * 32 + (c - 32)) =
            make_float4(qv[0], qv[1], qv[2], qv[3]);
    }
}

extern "C" void kernel_launch(void* const* d_in, const int* in_sizes, int n_in,
                              void* d_out, int out_size, void* d_ws, size_t ws_size,
                              hipStream_t stream) {
    (void)in_sizes; (void)n_in; (void)out_size; (void)ws_size;
    const float* x   = (const float*)d_in[0];
    const int*   ei  = (const int*)d_in[1];
    const float* W1  = (const float*)d_in[2];
    const float* W2  = (const float*)d_in[4];
    const float* g1  = (const float*)d_in[6];
    const float* be1 = (const float*)d_in[7];
    const float* g2  = (const float*)d_in[8];
    const float* be2 = (const float*)d_in[9];
    const float* Wm  = (const float*)d_in[10];
    const float* bm  = (const float*)d_in[11];
    const float* Wv  = (const float*)d_in[12];
    const float* bv  = (const float*)d_in[13];
    const float* Wt  = (const float*)d_in[14];
    const float* bt  = (const float*)d_in[15];
    const float* eps = (const float*)d_in[16];

    const int* e_src = ei;
    const int* e_dst = ei + N_EDGES;

    char* ws = (char*)d_ws;
    float* bufA    = (float*)(ws + OFF_BUFA);
    float* bufB    = (float*)(ws + OFF_BUFB);
    float* bufC    = (float*)(ws + OFF_BUFC);
    unsigned short* W1t = (unsigned short*)(ws + OFF_BUFC);  // 512KB, dead after gemm1
    int*   csr_src = (int*)(ws + OFF_CSRSRC);
    float* csr_w   = (float*)(ws + OFF_CSRW);
    int*   cnt     = (int*)(ws + OFF_CNT);
    int*   cnt2    = (int*)(ws + OFF_CNT2);
    int*   offs    = (int*)(ws + OFF_OFFS);
    float* dinv    = (float*)(ws + OFF_DINV);
    float* sumsA   = (float*)(ws + OFF_SUMSA);
    float* sumsB   = (float*)(ws + OFF_SUMSB);
    float* paramsA = (float*)(ws + OFF_PARAMSA);
    float* paramsB = (float*)(ws + OFF_PARAMSB);

    float* out_qz = (float*)d_out;
    float* out_qm = out_qz + N_NODES * ZDIM;
    float* out_qs = out_qm + N_NODES * ZDIM;
    float* out_t  = out_qs + N_NODES * ZDIM;

    const int MB = (N_NODES + 63) / 64;  // 782

    k_zero<<<(N_NODES + 255) / 256, 256, 0, stream>>>(cnt, cnt2, sumsA, sumsB);
    k_count<<<(N_EDGES + 255) / 256, 256, 0, stream>>>(e_dst, cnt);
    k_scan<<<1, 1024, 0, stream>>>(cnt, offs, dinv);
    k_fill<<<(N_EDGES + 255) / 256, 256, 0, stream>>>(e_src, e_dst, offs, cnt2, dinv,
                                                      csr_src, csr_w);
    k_prep<<<1024, 256, 0, stream>>>(W1, W1t);
    // layer 0
    k_gemm1m<<<MB, 256, 0, stream>>>(x, W1t, bufA);
    k_agg128<<<N_NODES / 8, 256, 0, stream>>>(bufA, offs, csr_src, csr_w, dinv, bufB);
    k_bnstats<<<256, 128, 0, stream>>>(bufB, sumsA);
    k_bnfin<<<1, 128, 0, stream>>>(sumsA, g1, be1, paramsA);
    // layer 1
    k_gemm2<<<MB, 256, 0, stream>>>(bufB, W2, paramsA, bufC, bufA);
    k_agg128<<<N_NODES / 8, 256, 0, stream>>>(bufA, offs, csr_src, csr_w, dinv, bufB);
    k_bnstats<<<256, 128, 0, stream>>>(bufB, sumsB);
    k_bnfin<<<1, 128, 0, stream>>>(sumsB, g2, be2, paramsB);
    // heads
    k_gemm3<<<MB, 256, 0, stream>>>(bufB, bufC, paramsB, Wm, Wv, Wt, bt, bufA, out_t);
    k_aggfin2<<<N_NODES / 16, 256, 0, stream>>>(bufA, offs, csr_src, csr_w, dinv,
                                                bm, bv, eps, out_qz, out_qm, out_qs);
}

// Round 3
// 663.472 us; speedup vs baseline: 1.9448x; 1.3091x over previous
//
#include <hip/hip_runtime.h>
#include <hip/hip_bf16.h>
#include <math.h>

#define N_NODES 50000
#define N_EDGES 1600000
#define DIN     2000
#define HDIM    128
#define ZDIM    32

// ---------------- workspace layout (bytes) ----------------
#define OFF_HA     0UL          // bf16 [N][128]  (gemm1 out, later gemm2 out)
#define OFF_HB     12800000UL   // bf16 [N][128]  (agg outputs)
#define OFF_H0RES  25600000UL   // bf16 [N][128]  residual h0
#define OFF_HMV    38400000UL   // bf16 [N][64]
#define OFF_W1T    44800000UL   // bf16 [128][2048]
#define OFF_W2T    45324288UL   // bf16 [128][128]
#define OFF_W3T    45357056UL   // bf16 [64][128]
#define OFF_CSRS   45373440UL   // int  [E]
#define OFF_CSRW   51773440UL   // f32  [E]
#define OFF_CNT    58173440UL
#define OFF_CNT2   58373440UL
#define OFF_OFFS   58573440UL
#define OFF_DINV   58773504UL
#define OFF_SUMSA  58973504UL
#define OFF_SUMSB  58974528UL
#define OFF_PARA   58975552UL
#define OFF_PARB   58976576UL

typedef __attribute__((ext_vector_type(8))) short short8;
typedef __attribute__((ext_vector_type(4))) float f32x4;

__device__ inline unsigned short f2bf(float f) {
    unsigned u = __builtin_bit_cast(unsigned, f);
    u += 0x7FFFu + ((u >> 16) & 1u);
    return (unsigned short)(u >> 16);
}
__device__ inline float bf2f(unsigned short u) {
    return __builtin_bit_cast(float, ((unsigned)u) << 16);
}
__device__ inline void ubf2(unsigned u, float& lo, float& hi) {
    lo = __builtin_bit_cast(float, u << 16);
    hi = __builtin_bit_cast(float, u & 0xFFFF0000u);
}
__device__ inline void gload_lds16(const unsigned short* g, unsigned short* l) {
    __builtin_amdgcn_global_load_lds(
        (const __attribute__((address_space(1))) unsigned int*)g,
        (__attribute__((address_space(3))) unsigned int*)l, 16, 0, 0);
}
__device__ inline f32x4 mfma16(short8 a, short8 b, f32x4 c) {
    return __builtin_amdgcn_mfma_f32_16x16x32_bf16(a, b, c, 0, 0, 0);
}

// ---------------- CSR build ----------------
__global__ void k_zero(int* cnt, int* cnt2, float* sumsA, float* sumsB) {
    int i = blockIdx.x * blockDim.x + threadIdx.x;
    if (i < N_NODES) { cnt[i] = 0; cnt2[i] = 0; }
    if (i < 256)     { sumsA[i] = 0.f; sumsB[i] = 0.f; }
}

__global__ void k_count(const int* __restrict__ dst, int* __restrict__ cnt) {
    int e = blockIdx.x * blockDim.x + threadIdx.x;
    if (e < N_EDGES) atomicAdd(&cnt[dst[e]], 1);
}

__global__ void k_scan(const int* __restrict__ cnt, int* __restrict__ offs,
                       float* __restrict__ dinv) {
    __shared__ int sums[1024];
    const int CH = (N_NODES + 1023) / 1024;
    int t = threadIdx.x;
    int base = t * CH;
    int s = 0;
    for (int i = 0; i < CH; ++i) {
        int idx = base + i;
        if (idx < N_NODES) s += cnt[idx];
    }
    sums[t] = s;
    __syncthreads();
    for (int d = 1; d < 1024; d <<= 1) {
        int v = sums[t];
        int add = (t >= d) ? sums[t - d] : 0;
        __syncthreads();
        sums[t] = v + add;
        __syncthreads();
    }
    int run = (t == 0) ? 0 : sums[t - 1];
    for (int i = 0; i < CH; ++i) {
        int idx = base + i;
        if (idx < N_NODES) {
            offs[idx] = run;
            int c = cnt[idx];
            run += c;
            dinv[idx] = rsqrtf((float)(c + 1));
        }
    }
    if (t == 1023) offs[N_NODES] = run;
}

__global__ void k_fill(const int* __restrict__ src, const int* __restrict__ dst,
                       const int* __restrict__ offs, int* __restrict__ cnt2,
                       const float* __restrict__ dinv,
                       int* __restrict__ csr_src, float* __restrict__ csr_w) {
    int e = blockIdx.x * blockDim.x + threadIdx.x;
    if (e >= N_EDGES) return;
    int d = dst[e], s = src[e];
    int p = atomicAdd(&cnt2[d], 1);
    int idx = offs[d] + p;
    csr_src[idx] = s;
    csr_w[idx] = dinv[s];
}

// ---------------- weight prep: W1t[128][2048], W2t[n][k], W3t[n][k] ----------
__global__ void k_prep(const float* __restrict__ W1, const float* __restrict__ W2,
                       const float* __restrict__ Wm, const float* __restrict__ Wv,
                       unsigned short* __restrict__ W1t, unsigned short* __restrict__ W2t,
                       unsigned short* __restrict__ W3t) {
    int b = blockIdx.x;
    int tid = threadIdx.x;
    if (b < 1024) {                       // W1t: 128 x 2048
        int idx = b * 256 + tid;
        int n = idx >> 11, k = idx & 2047;
        W1t[idx] = f2bf((k < DIN) ? W1[(size_t)k * HDIM + n] : 0.f);
    } else if (b < 1024 + 64) {           // W2t: 128 x 128 (transposed)
        int idx = (b - 1024) * 256 + tid;
        int n = idx >> 7, k = idx & 127;
        W2t[idx] = f2bf(W2[(size_t)k * HDIM + n]);
    } else {                              // W3t: 64 x 128  ([Wm|Wv] transposed)
        int idx = (b - 1088) * 256 + tid;
        int n = idx >> 7, k = idx & 127;
        W3t[idx] = f2bf((n < 32) ? Wm[(size_t)k * ZDIM + n]
                                 : Wv[(size_t)k * ZDIM + (n - 32)]);
    }
}

// ---------------- gemm1: x[N,2000](f32) @ W1 -> bf16 [N,128], MFMA ----------
#define G1_BM 64
#define G1_BK 64
__global__ __launch_bounds__(256) void k_gemm1m(const float* __restrict__ A,
                                                const unsigned short* __restrict__ Bt,
                                                unsigned short* __restrict__ C) {
    __shared__ __align__(16) unsigned short Abuf[2][G1_BM * G1_BK];
    __shared__ __align__(16) unsigned short Bbuf[2][HDIM * G1_BK];
    const int tid  = threadIdx.x;
    const int lane = tid & 63;
    const int wave = tid >> 6;
    const int m0   = blockIdx.x * G1_BM;
    const int wm   = (wave >> 1) * 32;
    const int wn   = (wave & 1) * 64;
    const int ar   = tid >> 2;
    const int acp  = tid & 3;

    f32x4 acc[2][4];
#pragma unroll
    for (int i = 0; i < 2; ++i)
#pragma unroll
        for (int j = 0; j < 4; ++j) acc[i][j] = (f32x4)0.f;

    float areg[16];

    auto stageA = [&](int k0) {
        const int g = m0 + ar;
        const int kk = k0 + acp * 16;
        if (g < N_NODES && kk < DIN) {
#pragma unroll
            for (int q = 0; q < 4; ++q)
                *(float4*)&areg[q * 4] = *(const float4*)(A + (size_t)g * DIN + kk + q * 4);
        } else {
#pragma unroll
            for (int q = 0; q < 16; ++q) areg[q] = 0.f;
        }
    };

    auto writeA = [&](int c) {
        unsigned short u[16];
#pragma unroll
        for (int q = 0; q < 16; ++q) u[q] = f2bf(areg[q]);
#pragma unroll
        for (int q = 0; q < 2; ++q) {
            int chunk = acp * 2 + q;
            int pos = chunk ^ (ar & 7);
            *(uint4*)&Abuf[c][ar * G1_BK + pos * 8] = *(const uint4*)&u[q * 8];
        }
    };

    auto issueB = [&](int k0, int c) {
#pragma unroll
        for (int q = 0; q < 4; ++q) {
            int nbase = wave * 32 + q * 8;
            int n = nbase + (lane >> 3);
            int pos = lane & 7;
            int ksrc = k0 + ((pos ^ (n & 7)) * 8);
            gload_lds16(Bt + (size_t)n * 2048 + ksrc, &Bbuf[c][nbase * G1_BK]);
        }
    };

    auto compute = [&](int c) {
        const int rl = lane & 15;
        const int kg = lane >> 4;
#pragma unroll
        for (int ks = 0; ks < 2; ++ks) {
            short8 a[2], b[4];
#pragma unroll
            for (int i = 0; i < 2; ++i) {
                int r = wm + i * 16 + rl;
                int pos = (kg + ks * 4) ^ (r & 7);
                a[i] = *(const short8*)&Abuf[c][r * G1_BK + pos * 8];
            }
#pragma unroll
            for (int j = 0; j < 4; ++j) {
                int n = wn + j * 16 + rl;
                int pos = (kg + ks * 4) ^ (n & 7);
                b[j] = *(const short8*)&Bbuf[c][n * G1_BK + pos * 8];
            }
#pragma unroll
            for (int i = 0; i < 2; ++i)
#pragma unroll
                for (int j = 0; j < 4; ++j)
                    acc[i][j] = mfma16(a[i], b[j], acc[i][j]);
        }
    };

    const int NT = 32;
    stageA(0);
    issueB(0, 0);
#pragma unroll 1
    for (int t = 0; t < NT; ++t) {
        const int c = t & 1;
        writeA(c);
        __syncthreads();
        if (t + 1 < NT) { stageA((t + 1) * G1_BK); issueB((t + 1) * G1_BK, c ^ 1); }
        compute(c);
        __syncthreads();
    }
#pragma unroll
    for (int i = 0; i < 2; ++i) {
        int rb = m0 + wm + i * 16 + (lane >> 4) * 4;
#pragma unroll
        for (int j = 0; j < 4; ++j) {
            int col = wn + j * 16 + (lane & 15);
#pragma unroll
            for (int r = 0; r < 4; ++r)
                if (rb + r < N_NODES) C[(size_t)(rb + r) * HDIM + col] = f2bf(acc[i][j][r]);
        }
    }
}

// ---------------- aggregation (128 ch, bf16 table) ---------------------------
__global__ __launch_bounds__(256) void k_aggb(const unsigned short* __restrict__ h,
        const int* __restrict__ offs, const int* __restrict__ csr_src,
        const float* __restrict__ csr_w, const float* __restrict__ dinv,
        unsigned short* __restrict__ out) {
    const int row = blockIdx.x * 8 + (threadIdx.x >> 5);
    const int c = (threadIdx.x & 31) * 4;
    const float di = dinv[row];
    uint2 hv = *(const uint2*)(h + (size_t)row * HDIM + c);
    float a0, a1, a2, a3, b0, b1;
    ubf2(hv.x, a0, a1); ubf2(hv.y, a2, a3);
    a0 *= di; a1 *= di; a2 *= di; a3 *= di;
    const int p1 = offs[row + 1];
#pragma unroll 4
    for (int p = offs[row]; p < p1; ++p) {
        int s = csr_src[p];
        float w = csr_w[p];
        uint2 v = *(const uint2*)(h + (size_t)s * HDIM + c);
        ubf2(v.x, b0, b1); a0 += w * b0; a1 += w * b1;
        ubf2(v.y, b0, b1); a2 += w * b0; a3 += w * b1;
    }
    unsigned short o[4];
    o[0] = f2bf(di * a0); o[1] = f2bf(di * a1);
    o[2] = f2bf(di * a2); o[3] = f2bf(di * a3);
    *(uint2*)(out + (size_t)row * HDIM + c) = *(const uint2*)o;
}

// ---------------- BN stats over bf16 table -----------------------------------
__global__ __launch_bounds__(256) void k_bnstatsb(const unsigned short* __restrict__ h,
                                                  float* __restrict__ sums) {
    const int c2 = threadIdx.x & 63;    // uint (2-channel) index
    const int rsub = threadIdx.x >> 6;  // 0..3
    float s0 = 0.f, s1 = 0.f, q0 = 0.f, q1 = 0.f;
    for (int r = blockIdx.x * 4 + rsub; r < N_NODES; r += 200 * 4) {
        unsigned u = *(const unsigned*)(h + (size_t)r * HDIM + c2 * 2);
        float lo, hi;
        ubf2(u, lo, hi);
        s0 += lo; q0 += lo * lo; s1 += hi; q1 += hi * hi;
    }
    __shared__ float red[256][4];
    red[threadIdx.x][0] = s0; red[threadIdx.x][1] = s1;
    red[threadIdx.x][2] = q0; red[threadIdx.x][3] = q1;
    __syncthreads();
    if (threadIdx.x < 64) {
#pragma unroll
        for (int k = 1; k < 4; ++k) {
            s0 += red[threadIdx.x + 64 * k][0];
            s1 += red[threadIdx.x + 64 * k][1];
            q0 += red[threadIdx.x + 64 * k][2];
            q1 += red[threadIdx.x + 64 * k][3];
        }
        atomicAdd(&sums[c2 * 2], s0);
        atomicAdd(&sums[c2 * 2 + 1], s1);
        atomicAdd(&sums[128 + c2 * 2], q0);
        atomicAdd(&sums[128 + c2 * 2 + 1], q1);
    }
}

__global__ void k_bnfin(const float* __restrict__ sums, const float* __restrict__ g,
                        const float* __restrict__ be, float* __restrict__ params) {
    int c = threadIdx.x;  // 128
    float mean = sums[c] * (1.f / N_NODES);
    float var = sums[128 + c] * (1.f / N_NODES) - mean * mean;
    float rstd = rsqrtf(var + 1e-5f);
    float sc = g[c] * rstd;
    params[c] = sc;
    params[128 + c] = be[c] - mean * sc;
}

// ---------------- gemm2: h0 = relu(bn(agg0)); h1 = h0 @ W2 (MFMA) -----------
__global__ __launch_bounds__(256) void k_gemm2m(const unsigned short* __restrict__ Ain,
        const unsigned short* __restrict__ W2t, const float* __restrict__ params,
        unsigned short* __restrict__ h0res, unsigned short* __restrict__ Hout) {
    __shared__ __align__(16) unsigned short As[64 * 128];
    __shared__ __align__(16) unsigned short Bs[128 * 128];
    const int tid = threadIdx.x, lane = tid & 63, wave = tid >> 6;
    const int m0 = blockIdx.x * 64;
    {   // stage A with BN+ReLU, emit h0res
        const int ar = tid >> 2, acp = tid & 3;
        const int g = m0 + ar;
        unsigned short u[32];
        if (g < N_NODES) {
#pragma unroll
            for (int q = 0; q < 4; ++q) {
                int kb = acp * 32 + q * 8;
                uint4 raw = *(const uint4*)(Ain + (size_t)g * HDIM + kb);
                float4 sc0 = *(const float4*)(params + kb);
                float4 sc1 = *(const float4*)(params + kb + 4);
                float4 sh0 = *(const float4*)(params + 128 + kb);
                float4 sh1 = *(const float4*)(params + 128 + kb + 4);
                const unsigned* pu = (const unsigned*)&raw;
                float v[8];
                ubf2(pu[0], v[0], v[1]); ubf2(pu[1], v[2], v[3]);
                ubf2(pu[2], v[4], v[5]); ubf2(pu[3], v[6], v[7]);
                u[q * 8 + 0] = f2bf(fmaxf(v[0] * sc0.x + sh0.x, 0.f));
                u[q * 8 + 1] = f2bf(fmaxf(v[1] * sc0.y + sh0.y, 0.f));
                u[q * 8 + 2] = f2bf(fmaxf(v[2] * sc0.z + sh0.z, 0.f));
                u[q * 8 + 3] = f2bf(fmaxf(v[3] * sc0.w + sh0.w, 0.f));
                u[q * 8 + 4] = f2bf(fmaxf(v[4] * sc1.x + sh1.x, 0.f));
                u[q * 8 + 5] = f2bf(fmaxf(v[5] * sc1.y + sh1.y, 0.f));
                u[q * 8 + 6] = f2bf(fmaxf(v[6] * sc1.z + sh1.z, 0.f));
                u[q * 8 + 7] = f2bf(fmaxf(v[7] * sc1.w + sh1.w, 0.f));
            }
#pragma unroll
            for (int q = 0; q < 4; ++q)
                *(uint4*)(h0res + (size_t)g * HDIM + acp * 32 + q * 8) = *(const uint4*)&u[q * 8];
        } else {
#pragma unroll
            for (int q = 0; q < 32; ++q) u[q] = 0;
        }
#pragma unroll
        for (int q = 0; q < 4; ++q) {
            int ch = acp * 4 + q;
            int pos = ch ^ (ar & 7);
            *(uint4*)&As[ar * 128 + pos * 8] = *(const uint4*)&u[q * 8];
        }
    }
    {   // stage B (W2t [n][k]) swizzled
        const int br = tid >> 1, half = tid & 1;
#pragma unroll
        for (int q = 0; q < 8; ++q) {
            int ch = half * 8 + q;
            int pos = ch ^ (br & 7);
            *(uint4*)&Bs[br * 128 + pos * 8] =
                *(const uint4*)(W2t + (size_t)br * 128 + ch * 8);
        }
    }
    __syncthreads();
    const int wm = (wave >> 1) * 32, wn = (wave & 1) * 64;
    const int rl = lane & 15, kg = lane >> 4;
    f32x4 acc[2][4];
#pragma unroll
    for (int i = 0; i < 2; ++i)
#pragma unroll
        for (int j = 0; j < 4; ++j) acc[i][j] = (f32x4)0.f;
#pragma unroll
    for (int ks = 0; ks < 4; ++ks) {
        short8 a[2], b[4];
        int ch = ks * 4 + kg;
#pragma unroll
        for (int i = 0; i < 2; ++i) {
            int r = wm + i * 16 + rl;
            a[i] = *(const short8*)&As[r * 128 + (ch ^ (r & 7)) * 8];
        }
#pragma unroll
        for (int j = 0; j < 4; ++j) {
            int n = wn + j * 16 + rl;
            b[j] = *(const short8*)&Bs[n * 128 + (ch ^ (n & 7)) * 8];
        }
#pragma unroll
        for (int i = 0; i < 2; ++i)
#pragma unroll
            for (int j = 0; j < 4; ++j) acc[i][j] = mfma16(a[i], b[j], acc[i][j]);
    }
#pragma unroll
    for (int i = 0; i < 2; ++i) {
        int rb = m0 + wm + i * 16 + (lane >> 4) * 4;
#pragma unroll
        for (int j = 0; j < 4; ++j) {
            int col = wn + j * 16 + rl;
#pragma unroll
            for (int r = 0; r < 4; ++r)
                if (rb + r < N_NODES) Hout[(size_t)(rb + r) * HDIM + col] = f2bf(acc[i][j][r]);
        }
    }
}

// ------ gemm3: h = relu(bn(agg1)) + h0res; hmv = h@[Wm|Wv]; t = sigmoid(h@Wt+bt)
__global__ __launch_bounds__(256) void k_gemm3m(const unsigned short* __restrict__ Ain,
        const unsigned short* __restrict__ h0res, const float* __restrict__ params,
        const unsigned short* __restrict__ W3t, const float* __restrict__ Wt,
        const float* __restrict__ bt,
        unsigned short* __restrict__ hmv, float* __restrict__ t_out) {
    __shared__ __align__(16) unsigned short As[64 * 128];
    __shared__ __align__(16) unsigned short Bs[64 * 128];
    __shared__ float WtS[128];
    const int tid = threadIdx.x, lane = tid & 63, wave = tid >> 6;
    const int m0 = blockIdx.x * 64;
    {   // stage A: relu(bn(agg1)) + h0res
        const int ar = tid >> 2, acp = tid & 3;
        const int g = m0 + ar;
        unsigned short u[32];
        if (g < N_NODES) {
#pragma unroll
            for (int q = 0; q < 4; ++q) {
                int kb = acp * 32 + q * 8;
                uint4 raw = *(const uint4*)(Ain + (size_t)g * HDIM + kb);
                uint4 res = *(const uint4*)(h0res + (size_t)g * HDIM + kb);
                float4 sc0 = *(const float4*)(params + kb);
                float4 sc1 = *(const float4*)(params + kb + 4);
                float4 sh0 = *(const float4*)(params + 128 + kb);
                float4 sh1 = *(const float4*)(params + 128 + kb + 4);
                const unsigned* pu = (const unsigned*)&raw;
                const unsigned* pr = (const unsigned*)&res;
                float v[8], rr[8];
                ubf2(pu[0], v[0], v[1]); ubf2(pu[1], v[2], v[3]);
                ubf2(pu[2], v[4], v[5]); ubf2(pu[3], v[6], v[7]);
                ubf2(pr[0], rr[0], rr[1]); ubf2(pr[1], rr[2], rr[3]);
                ubf2(pr[2], rr[4], rr[5]); ubf2(pr[3], rr[6], rr[7]);
                u[q * 8 + 0] = f2bf(fmaxf(v[0] * sc0.x + sh0.x, 0.f) + rr[0]);
                u[q * 8 + 1] = f2bf(fmaxf(v[1] * sc0.y + sh0.y, 0.f) + rr[1]);
                u[q * 8 + 2] = f2bf(fmaxf(v[2] * sc0.z + sh0.z, 0.f) + rr[2]);
                u[q * 8 + 3] = f2bf(fmaxf(v[3] * sc0.w + sh0.w, 0.f) + rr[3]);
                u[q * 8 + 4] = f2bf(fmaxf(v[4] * sc1.x + sh1.x, 0.f) + rr[4]);
                u[q * 8 + 5] = f2bf(fmaxf(v[5] * sc1.y + sh1.y, 0.f) + rr[5]);
                u[q * 8 + 6] = f2bf(fmaxf(v[6] * sc1.z + sh1.z, 0.f) + rr[6]);
                u[q * 8 + 7] = f2bf(fmaxf(v[7] * sc1.w + sh1.w, 0.f) + rr[7]);
            }
        } else {
#pragma unroll
            for (int q = 0; q < 32; ++q) u[q] = 0;
        }
#pragma unroll
        for (int q = 0; q < 4; ++q) {
            int ch = acp * 4 + q;
            int pos = ch ^ (ar & 7);
            *(uint4*)&As[ar * 128 + pos * 8] = *(const uint4*)&u[q * 8];
        }
    }
    {   // stage B (W3t [64][128]) swizzled
        const int br = tid >> 2, chq = tid & 3;
#pragma unroll
        for (int q = 0; q < 4; ++q) {
            int ch = chq * 4 + q;
            int pos = ch ^ (br & 7);
            *(uint4*)&Bs[br * 128 + pos * 8] =
                *(const uint4*)(W3t + (size_t)br * 128 + ch * 8);
        }
    }
    if (tid < 128) WtS[tid] = Wt[tid];
    __syncthreads();
    const int wm = (wave >> 1) * 32, wn = (wave & 1) * 32;
    const int rl = lane & 15, kg = lane >> 4;
    f32x4 acc[2][2];
#pragma unroll
    for (int i = 0; i < 2; ++i)
#pragma unroll
        for (int j = 0; j < 2; ++j) acc[i][j] = (f32x4)0.f;
#pragma unroll
    for (int ks = 0; ks < 4; ++ks) {
        short8 a[2], b[2];
        int ch = ks * 4 + kg;
#pragma unroll
        for (int i = 0; i < 2; ++i) {
            int r = wm + i * 16 + rl;
            a[i] = *(const short8*)&As[r * 128 + (ch ^ (r & 7)) * 8];
        }
#pragma unroll
        for (int j = 0; j < 2; ++j) {
            int n = wn + j * 16 + rl;
            b[j] = *(const short8*)&Bs[n * 128 + (ch ^ (n & 7)) * 8];
        }
#pragma unroll
        for (int i = 0; i < 2; ++i)
#pragma unroll
            for (int j = 0; j < 2; ++j) acc[i][j] = mfma16(a[i], b[j], acc[i][j]);
    }
#pragma unroll
    for (int i = 0; i < 2; ++i) {
        int rb = m0 + wm + i * 16 + (lane >> 4) * 4;
#pragma unroll
        for (int j = 0; j < 2; ++j) {
            int col = wn + j * 16 + rl;
#pragma unroll
            for (int r = 0; r < 4; ++r)
                if (rb + r < N_NODES) hmv[(size_t)(rb + r) * 64 + col] = f2bf(acc[i][j][r]);
        }
    }
    // t-head: 4 lanes per row over LDS bf16 h
    {
        const int r = wave * 16 + (lane & 15);
        const int sub = lane >> 4;
        float s = 0.f;
#pragma unroll
        for (int q = 0; q < 4; ++q) {
            int ch = sub * 4 + q;
            short8 v = *(const short8*)&As[r * 128 + (ch ^ (r & 7)) * 8];
#pragma unroll
            for (int e = 0; e < 8; ++e)
                s += bf2f((unsigned short)v[e]) * WtS[ch * 8 + e];
        }
        s += __shfl_xor(s, 16);
        s += __shfl_xor(s, 32);
        if (sub == 0 && (m0 + r) < N_NODES)
            t_out[m0 + r] = 1.f / (1.f + expf(-(s + bt[0])));
    }
}

// ---------------- final aggregation (64 ch bf16) + VAE epilogue --------------
__global__ __launch_bounds__(256) void k_aggfin3(const unsigned short* __restrict__ hmv,
        const int* __restrict__ offs, const int* __restrict__ csr_src,
        const float* __restrict__ csr_w, const float* __restrict__ dinv,
        const float* __restrict__ bm, const float* __restrict__ bv,
        const float* __restrict__ eps,
        float* __restrict__ out_qz, float* __restrict__ out_qm,
        float* __restrict__ out_qs) {
    const int row = blockIdx.x * 16 + (threadIdx.x >> 4);
    const int cq = threadIdx.x & 15;
    const int c = cq * 4;
    const float di = dinv[row];
    uint2 hv = *(const uint2*)(hmv + (size_t)row * 64 + c);
    float a0, a1, a2, a3, b0, b1;
    ubf2(hv.x, a0, a1); ubf2(hv.y, a2, a3);
    a0 *= di; a1 *= di; a2 *= di; a3 *= di;
    const int p1 = offs[row + 1];
#pragma unroll 4
    for (int p = offs[row]; p < p1; ++p) {
        int s = csr_src[p];
        float w = csr_w[p];
        uint2 v = *(const uint2*)(hmv + (size_t)s * 64 + c);
        ubf2(v.x, b0, b1); a0 += w * b0; a1 += w * b1;
        ubf2(v.y, b0, b1); a2 += w * b0; a3 += w * b1;
    }
    float qv[4];
    const bool lo = cq < 8;
    if (lo) {
        qv[0] = di * a0 + bm[c + 0]; qv[1] = di * a1 + bm[c + 1];
        qv[2] = di * a2 + bm[c + 2]; qv[3] = di * a3 + bm[c + 3];
    } else {
        qv[0] = di * a0 + bv[c - 32 + 0]; qv[1] = di * a1 + bv[c - 32 + 1];
        qv[2] = di * a2 + bv[c - 32 + 2]; qv[3] = di * a3 + bv[c - 32 + 3];
    }
    float sp[4] = {0.f, 0.f, 0.f, 0.f};
    if (!lo) {
#pragma unroll
        for (int k = 0; k < 4; ++k)
            sp[k] = fmaxf(qv[k], 0.f) + log1pf(expf(-fabsf(qv[k]))) + 1e-6f;
    }
    float spx[4];
#pragma unroll
    for (int k = 0; k < 4; ++k) spx[k] = __shfl_xor(sp[k], 8);
    if (lo) {
        *(float4*)(out_qm + (size_t)row * 32 + c) = make_float4(qv[0], qv[1], qv[2], qv[3]);
        float4 e = *(const float4*)(eps + (size_t)row * 32 + c);
        float4 qz;
        qz.x = qv[0] + spx[0] * e.x; qz.y = qv[1] + spx[1] * e.y;
        qz.z = qv[2] + spx[2] * e.z; qz.w = qv[3] + spx[3] * e.w;
        *(float4*)(out_qz + (size_t)row * 32 + c) = qz;
    } else {
        *(float4*)(out_qs + (size_t)row * 32 + (c - 32)) =
            make_float4(qv[0], qv[1], qv[2], qv[3]);
    }
}

extern "C" void kernel_launch(void* const* d_in, const int* in_sizes, int n_in,
                              void* d_out, int out_size, void* d_ws, size_t ws_size,
                              hipStream_t stream) {
    (void)in_sizes; (void)n_in; (void)out_size; (void)ws_size;
    const float* x   = (const float*)d_in[0];
    const int*   ei  = (const int*)d_in[1];
    const float* W1  = (const float*)d_in[2];
    const float* W2  = (const float*)d_in[4];
    const float* g1  = (const float*)d_in[6];
    const float* be1 = (const float*)d_in[7];
    const float* g2  = (const float*)d_in[8];
    const float* be2 = (const float*)d_in[9];
    const float* Wm  = (const float*)d_in[10];
    const float* bm  = (const float*)d_in[11];
    const float* Wv  = (const float*)d_in[12];
    const float* bv  = (const float*)d_in[13];
    const float* Wt  = (const float*)d_in[14];
    const float* bt  = (const float*)d_in[15];
    const float* eps = (const float*)d_in[16];

    const int* e_src = ei;
    const int* e_dst = ei + N_EDGES;

    char* ws = (char*)d_ws;
    unsigned short* HA    = (unsigned short*)(ws + OFF_HA);
    unsigned short* HB    = (unsigned short*)(ws + OFF_HB);
    unsigned short* H0RES = (unsigned short*)(ws + OFF_H0RES);
    unsigned short* HMV   = (unsigned short*)(ws + OFF_HMV);
    unsigned short* W1t   = (unsigned short*)(ws + OFF_W1T);
    unsigned short* W2t   = (unsigned short*)(ws + OFF_W2T);
    unsigned short* W3t   = (unsigned short*)(ws + OFF_W3T);
    int*   csr_src = (int*)(ws + OFF_CSRS);
    float* csr_w   = (float*)(ws + OFF_CSRW);
    int*   cnt     = (int*)(ws + OFF_CNT);
    int*   cnt2    = (int*)(ws + OFF_CNT2);
    int*   offs    = (int*)(ws + OFF_OFFS);
    float* dinv    = (float*)(ws + OFF_DINV);
    float* sumsA   = (float*)(ws + OFF_SUMSA);
    float* sumsB   = (float*)(ws + OFF_SUMSB);
    float* paramsA = (float*)(ws + OFF_PARA);
    float* paramsB = (float*)(ws + OFF_PARB);

    float* out_qz = (float*)d_out;
    float* out_qm = out_qz + N_NODES * ZDIM;
    float* out_qs = out_qm + N_NODES * ZDIM;
    float* out_t  = out_qs + N_NODES * ZDIM;

    const int MB = (N_NODES + 63) / 64;  // 782

    k_zero<<<(N_NODES + 255) / 256, 256, 0, stream>>>(cnt, cnt2, sumsA, sumsB);
    k_count<<<(N_EDGES + 255) / 256, 256, 0, stream>>>(e_dst, cnt);
    k_scan<<<1, 1024, 0, stream>>>(cnt, offs, dinv);
    k_fill<<<(N_EDGES + 255) / 256, 256, 0, stream>>>(e_src, e_dst, offs, cnt2, dinv,
                                                      csr_src, csr_w);
    k_prep<<<1120, 256, 0, stream>>>(W1, W2, Wm, Wv, W1t, W2t, W3t);
    // layer 0
    k_gemm1m<<<MB, 256, 0, stream>>>(x, W1t, HA);
    k_aggb<<<N_NODES / 8, 256, 0, stream>>>(HA, offs, csr_src, csr_w, dinv, HB);
    k_bnstatsb<<<200, 256, 0, stream>>>(HB, sumsA);
    k_bnfin<<<1, 128, 0, stream>>>(sumsA, g1, be1, paramsA);
    // layer 1
    k_gemm2m<<<MB, 256, 0, stream>>>(HB, W2t, paramsA, H0RES, HA);
    k_aggb<<<N_NODES / 8, 256, 0, stream>>>(HA, offs, csr_src, csr_w, dinv, HB);
    k_bnstatsb<<<200, 256, 0, stream>>>(HB, sumsB);
    k_bnfin<<<1, 128, 0, stream>>>(sumsB, g2, be2, paramsB);
    // heads
    k_gemm3m<<<MB, 256, 0, stream>>>(HB, H0RES, paramsB, W3t, Wt, bt, HMV, out_t);
    k_aggfin3<<<N_NODES / 16, 256, 0, stream>>>(HMV, offs, csr_src, csr_w, dinv,
                                                bm, bv, eps, out_qz, out_qm, out_qs);
}

// Round 4
// 652.120 us; speedup vs baseline: 1.9787x; 1.0174x over previous
//
#include <hip/hip_runtime.h>
#include <hip/hip_bf16.h>
#include <math.h>

#define N_NODES 50000
#define N_EDGES 1600000
#define DIN     2000
#define HDIM    128
#define ZDIM    32

// ---------------- workspace layout (bytes) ----------------
#define OFF_HA     0UL          // bf16 [N][128]
#define OFF_HB     12800000UL   // bf16 [N][128]
#define OFF_H0RES  25600000UL   // bf16 [N][128]
#define OFF_HMV    38400000UL   // bf16 [N][64]
#define OFF_W1T    44800000UL   // bf16 [128][2048]
#define OFF_W2T    45324288UL   // bf16 [128][128]
#define OFF_W3T    45357056UL   // bf16 [64][128]
#define OFF_CSRS   45373440UL   // int  [E]
#define OFF_CSRW   51773440UL   // f32  [E]
#define OFF_CNT    58173440UL
#define OFF_CNT2   58373440UL
#define OFF_OFFS   58573440UL
#define OFF_DINV   58773504UL
#define OFF_SUMSA  58973504UL
#define OFF_SUMSB  58974528UL

typedef __attribute__((ext_vector_type(8))) short short8;
typedef __attribute__((ext_vector_type(4))) float f32x4;

__device__ inline unsigned short f2bf(float f) {
    unsigned u = __builtin_bit_cast(unsigned, f);
    u += 0x7FFFu + ((u >> 16) & 1u);
    return (unsigned short)(u >> 16);
}
__device__ inline float bf2f(unsigned short u) {
    return __builtin_bit_cast(float, ((unsigned)u) << 16);
}
__device__ inline void ubf2(unsigned u, float& lo, float& hi) {
    lo = __builtin_bit_cast(float, u << 16);
    hi = __builtin_bit_cast(float, u & 0xFFFF0000u);
}
__device__ inline void unpack8(uint4 v, float* f) {
    ubf2(v.x, f[0], f[1]); ubf2(v.y, f[2], f[3]);
    ubf2(v.z, f[4], f[5]); ubf2(v.w, f[6], f[7]);
}
__device__ inline void gload_lds16(const unsigned short* g, unsigned short* l) {
    __builtin_amdgcn_global_load_lds(
        (const __attribute__((address_space(1))) unsigned int*)g,
        (__attribute__((address_space(3))) unsigned int*)l, 16, 0, 0);
}
__device__ inline f32x4 mfma16(short8 a, short8 b, f32x4 c) {
    return __builtin_amdgcn_mfma_f32_16x16x32_bf16(a, b, c, 0, 0, 0);
}

// ------------- prep: weight transposes + zero counters/sums ------------------
__global__ void k_prep(const float* __restrict__ W1, const float* __restrict__ W2,
                       const float* __restrict__ Wm, const float* __restrict__ Wv,
                       unsigned short* __restrict__ W1t, unsigned short* __restrict__ W2t,
                       unsigned short* __restrict__ W3t,
                       int* __restrict__ cnt, int* __restrict__ cnt2,
                       float* __restrict__ sumsA, float* __restrict__ sumsB) {
    int b = blockIdx.x;
    int tid = threadIdx.x;
    if (b < 1024) {                       // W1t: 128 x 2048
        int idx = b * 256 + tid;
        int n = idx >> 11, k = idx & 2047;
        W1t[idx] = f2bf((k < DIN) ? W1[(size_t)k * HDIM + n] : 0.f);
    } else if (b < 1088) {                // W2t: 128 x 128 (transposed)
        int idx = (b - 1024) * 256 + tid;
        int n = idx >> 7, k = idx & 127;
        W2t[idx] = f2bf(W2[(size_t)k * HDIM + n]);
    } else if (b < 1120) {                // W3t: 64 x 128 ([Wm|Wv] transposed)
        int idx = (b - 1088) * 256 + tid;
        int n = idx >> 7, k = idx & 127;
        W3t[idx] = f2bf((n < 32) ? Wm[(size_t)k * ZDIM + n]
                                 : Wv[(size_t)k * ZDIM + (n - 32)]);
    } else if (b < 1316) {                // zero cnt, cnt2
        int idx = (b - 1120) * 256 + tid;
        if (idx < N_NODES) { cnt[idx] = 0; cnt2[idx] = 0; }
    } else if (b == 1316) {
        sumsA[tid] = 0.f;
    } else {
        sumsB[tid] = 0.f;
    }
}

// ---------------- CSR build ----------------
__global__ void k_count(const int* __restrict__ dst, int* __restrict__ cnt) {
    int e4 = blockIdx.x * blockDim.x + threadIdx.x;
    if (e4 >= N_EDGES / 4) return;
    int4 d = *(const int4*)(dst + e4 * 4);
    atomicAdd(&cnt[d.x], 1);
    atomicAdd(&cnt[d.y], 1);
    atomicAdd(&cnt[d.z], 1);
    atomicAdd(&cnt[d.w], 1);
}

__global__ void k_scan(const int* __restrict__ cnt, int* __restrict__ offs,
                       float* __restrict__ dinv) {
    __shared__ int sums[1024];
    const int CH = (N_NODES + 1023) / 1024;
    int t = threadIdx.x;
    int base = t * CH;
    int s = 0;
    for (int i = 0; i < CH; ++i) {
        int idx = base + i;
        if (idx < N_NODES) s += cnt[idx];
    }
    sums[t] = s;
    __syncthreads();
    for (int d = 1; d < 1024; d <<= 1) {
        int v = sums[t];
        int add = (t >= d) ? sums[t - d] : 0;
        __syncthreads();
        sums[t] = v + add;
        __syncthreads();
    }
    int run = (t == 0) ? 0 : sums[t - 1];
    for (int i = 0; i < CH; ++i) {
        int idx = base + i;
        if (idx < N_NODES) {
            offs[idx] = run;
            int c = cnt[idx];
            run += c;
            dinv[idx] = rsqrtf((float)(c + 1));
        }
    }
    if (t == 1023) offs[N_NODES] = run;
}

__global__ void k_fill(const int* __restrict__ src, const int* __restrict__ dst,
                       const int* __restrict__ offs, int* __restrict__ cnt2,
                       const float* __restrict__ dinv,
                       int* __restrict__ csr_src, float* __restrict__ csr_w) {
    int e4 = blockIdx.x * blockDim.x + threadIdx.x;
    if (e4 >= N_EDGES / 4) return;
    int4 s4 = *(const int4*)(src + e4 * 4);
    int4 d4 = *(const int4*)(dst + e4 * 4);
    const int ss[4] = {s4.x, s4.y, s4.z, s4.w};
    const int dd[4] = {d4.x, d4.y, d4.z, d4.w};
#pragma unroll
    for (int q = 0; q < 4; ++q) {
        int p = atomicAdd(&cnt2[dd[q]], 1);
        int idx = offs[dd[q]] + p;
        csr_src[idx] = ss[q];
        csr_w[idx] = dinv[ss[q]];
    }
}

// ---------------- gemm1: x[N,2000](f32) @ W1 -> bf16 [N,128], MFMA ----------
#define G1_BM 64
#define G1_BK 64
__global__ __launch_bounds__(256) void k_gemm1m(const float* __restrict__ A,
                                                const unsigned short* __restrict__ Bt,
                                                unsigned short* __restrict__ C) {
    __shared__ __align__(16) unsigned short Abuf[2][G1_BM * G1_BK];
    __shared__ __align__(16) unsigned short Bbuf[2][HDIM * G1_BK];
    const int tid  = threadIdx.x;
    const int lane = tid & 63;
    const int wave = tid >> 6;
    const int m0   = blockIdx.x * G1_BM;
    const int wm   = (wave >> 1) * 32;
    const int wn   = (wave & 1) * 64;
    const int ar   = tid >> 2;
    const int acp  = tid & 3;

    f32x4 acc[2][4];
#pragma unroll
    for (int i = 0; i < 2; ++i)
#pragma unroll
        for (int j = 0; j < 4; ++j) acc[i][j] = (f32x4)0.f;

    float areg[16];

    auto stageA = [&](int k0) {
        const int g = m0 + ar;
        const int kk = k0 + acp * 16;
        if (g < N_NODES && kk < DIN) {
#pragma unroll
            for (int q = 0; q < 4; ++q)
                *(float4*)&areg[q * 4] = *(const float4*)(A + (size_t)g * DIN + kk + q * 4);
        } else {
#pragma unroll
            for (int q = 0; q < 16; ++q) areg[q] = 0.f;
        }
    };

    auto writeA = [&](int c) {
        unsigned short u[16];
#pragma unroll
        for (int q = 0; q < 16; ++q) u[q] = f2bf(areg[q]);
#pragma unroll
        for (int q = 0; q < 2; ++q) {
            int chunk = acp * 2 + q;
            int pos = chunk ^ (ar & 7);
            *(uint4*)&Abuf[c][ar * G1_BK + pos * 8] = *(const uint4*)&u[q * 8];
        }
    };

    auto issueB = [&](int k0, int c) {
#pragma unroll
        for (int q = 0; q < 4; ++q) {
            int nbase = wave * 32 + q * 8;
            int n = nbase + (lane >> 3);
            int pos = lane & 7;
            int ksrc = k0 + ((pos ^ (n & 7)) * 8);
            gload_lds16(Bt + (size_t)n * 2048 + ksrc, &Bbuf[c][nbase * G1_BK]);
        }
    };

    auto compute = [&](int c) {
        const int rl = lane & 15;
        const int kg = lane >> 4;
#pragma unroll
        for (int ks = 0; ks < 2; ++ks) {
            short8 a[2], b[4];
#pragma unroll
            for (int i = 0; i < 2; ++i) {
                int r = wm + i * 16 + rl;
                int pos = (kg + ks * 4) ^ (r & 7);
                a[i] = *(const short8*)&Abuf[c][r * G1_BK + pos * 8];
            }
#pragma unroll
            for (int j = 0; j < 4; ++j) {
                int n = wn + j * 16 + rl;
                int pos = (kg + ks * 4) ^ (n & 7);
                b[j] = *(const short8*)&Bbuf[c][n * G1_BK + pos * 8];
            }
#pragma unroll
            for (int i = 0; i < 2; ++i)
#pragma unroll
                for (int j = 0; j < 4; ++j)
                    acc[i][j] = mfma16(a[i], b[j], acc[i][j]);
        }
    };

    const int NT = 32;
    stageA(0);
    issueB(0, 0);
#pragma unroll 1
    for (int t = 0; t < NT; ++t) {
        const int c = t & 1;
        writeA(c);
        __syncthreads();
        if (t + 1 < NT) { stageA((t + 1) * G1_BK); issueB((t + 1) * G1_BK, c ^ 1); }
        compute(c);
        __syncthreads();
    }
#pragma unroll
    for (int i = 0; i < 2; ++i) {
        int rb = m0 + wm + i * 16 + (lane >> 4) * 4;
#pragma unroll
        for (int j = 0; j < 4; ++j) {
            int col = wn + j * 16 + (lane & 15);
#pragma unroll
            for (int r = 0; r < 4; ++r)
                if (rb + r < N_NODES) C[(size_t)(rb + r) * HDIM + col] = f2bf(acc[i][j][r]);
        }
    }
}

// -------- fused aggregation (128 ch, uint4 gather) + BN partial stats --------
__global__ __launch_bounds__(256) void k_aggs(const unsigned short* __restrict__ h,
        const int* __restrict__ offs, const int* __restrict__ csr_src,
        const float* __restrict__ csr_w, const float* __restrict__ dinv,
        unsigned short* __restrict__ out, float* __restrict__ sums) {
    __shared__ float redS[16][128];
    __shared__ float redQ[16][128];
    const int rg = threadIdx.x >> 4;   // 0..15 row group
    const int lg = threadIdx.x & 15;   // channel octet
    const int c = lg * 8;
    float ssum[8] = {}, sq[8] = {};
#pragma unroll 1
    for (int it = 0; it < 4; ++it) {
        const int row = blockIdx.x * 64 + it * 16 + rg;
        if (row < N_NODES) {
            const float di = dinv[row];
            float a[8];
            unpack8(*(const uint4*)(h + (size_t)row * HDIM + c), a);
#pragma unroll
            for (int i = 0; i < 8; ++i) a[i] *= di;
            const int p1 = offs[row + 1];
#pragma unroll 2
            for (int p = offs[row]; p < p1; ++p) {
                int s = csr_src[p];
                float w = csr_w[p];
                float v[8];
                unpack8(*(const uint4*)(h + (size_t)s * HDIM + c), v);
#pragma unroll
                for (int i = 0; i < 8; ++i) a[i] += w * v[i];
            }
            unsigned short o[8];
#pragma unroll
            for (int i = 0; i < 8; ++i) {
                float ov = di * a[i];
                o[i] = f2bf(ov);
                ssum[i] += ov;
                sq[i] += ov * ov;
            }
            *(uint4*)(out + (size_t)row * HDIM + c) = *(const uint4*)o;
        }
    }
#pragma unroll
    for (int i = 0; i < 8; i += 4) {
        *(float4*)&redS[rg][c + i] = *(const float4*)&ssum[i];
        *(float4*)&redQ[rg][c + i] = *(const float4*)&sq[i];
    }
    __syncthreads();
    if (threadIdx.x < 128) {
        const int ch = threadIdx.x;
        float s = 0.f, q = 0.f;
#pragma unroll
        for (int g = 0; g < 16; ++g) { s += redS[g][ch]; q += redQ[g][ch]; }
        atomicAdd(&sums[ch], s);
        atomicAdd(&sums[128 + ch], q);
    }
}

// ------- gemm2: params from sums; h0 = relu(bn(agg0)); h1 = h0 @ W2 ---------
__global__ __launch_bounds__(256) void k_gemm2m(const unsigned short* __restrict__ Ain,
        const unsigned short* __restrict__ W2t, const float* __restrict__ sums,
        const float* __restrict__ gg, const float* __restrict__ beta,
        unsigned short* __restrict__ h0res, unsigned short* __restrict__ Hout) {
    __shared__ __align__(16) unsigned short As[64 * 128];
    __shared__ __align__(16) unsigned short Bs[128 * 128];
    __shared__ float prm[256];
    const int tid = threadIdx.x, lane = tid & 63, wave = tid >> 6;
    const int m0 = blockIdx.x * 64;
    if (tid < 128) {
        float mean = sums[tid] * (1.f / N_NODES);
        float var = sums[128 + tid] * (1.f / N_NODES) - mean * mean;
        float rstd = rsqrtf(var + 1e-5f);
        float sc = gg[tid] * rstd;
        prm[tid] = sc;
        prm[128 + tid] = beta[tid] - mean * sc;
    }
    __syncthreads();
    {   // stage A with BN+ReLU, emit h0res
        const int ar = tid >> 2, acp = tid & 3;
        const int g = m0 + ar;
        unsigned short u[32];
        if (g < N_NODES) {
#pragma unroll
            for (int q = 0; q < 4; ++q) {
                int kb = acp * 32 + q * 8;
                float v[8];
                unpack8(*(const uint4*)(Ain + (size_t)g * HDIM + kb), v);
#pragma unroll
                for (int e = 0; e < 8; ++e)
                    u[q * 8 + e] = f2bf(fmaxf(v[e] * prm[kb + e] + prm[128 + kb + e], 0.f));
            }
#pragma unroll
            for (int q = 0; q < 4; ++q)
                *(uint4*)(h0res + (size_t)g * HDIM + acp * 32 + q * 8) = *(const uint4*)&u[q * 8];
        } else {
#pragma unroll
            for (int q = 0; q < 32; ++q) u[q] = 0;
        }
#pragma unroll
        for (int q = 0; q < 4; ++q) {
            int ch = acp * 4 + q;
            int pos = ch ^ (ar & 7);
            *(uint4*)&As[ar * 128 + pos * 8] = *(const uint4*)&u[q * 8];
        }
    }
    {   // stage B (W2t [n][k]) swizzled
        const int br = tid >> 1, half = tid & 1;
#pragma unroll
        for (int q = 0; q < 8; ++q) {
            int ch = half * 8 + q;
            int pos = ch ^ (br & 7);
            *(uint4*)&Bs[br * 128 + pos * 8] =
                *(const uint4*)(W2t + (size_t)br * 128 + ch * 8);
        }
    }
    __syncthreads();
    const int wm = (wave >> 1) * 32, wn = (wave & 1) * 64;
    const int rl = lane & 15, kg = lane >> 4;
    f32x4 acc[2][4];
#pragma unroll
    for (int i = 0; i < 2; ++i)
#pragma unroll
        for (int j = 0; j < 4; ++j) acc[i][j] = (f32x4)0.f;
#pragma unroll
    for (int ks = 0; ks < 4; ++ks) {
        short8 a[2], b[4];
        int ch = ks * 4 + kg;
#pragma unroll
        for (int i = 0; i < 2; ++i) {
            int r = wm + i * 16 + rl;
            a[i] = *(const short8*)&As[r * 128 + (ch ^ (r & 7)) * 8];
        }
#pragma unroll
        for (int j = 0; j < 4; ++j) {
            int n = wn + j * 16 + rl;
            b[j] = *(const short8*)&Bs[n * 128 + (ch ^ (n & 7)) * 8];
        }
#pragma unroll
        for (int i = 0; i < 2; ++i)
#pragma unroll
            for (int j = 0; j < 4; ++j) acc[i][j] = mfma16(a[i], b[j], acc[i][j]);
    }
#pragma unroll
    for (int i = 0; i < 2; ++i) {
        int rb = m0 + wm + i * 16 + (lane >> 4) * 4;
#pragma unroll
        for (int j = 0; j < 4; ++j) {
            int col = wn + j * 16 + rl;
#pragma unroll
            for (int r = 0; r < 4; ++r)
                if (rb + r < N_NODES) Hout[(size_t)(rb + r) * HDIM + col] = f2bf(acc[i][j][r]);
        }
    }
}

// -- gemm3: params from sums; h = relu(bn(agg1))+h0res; hmv = h@[Wm|Wv]; t-head
__global__ __launch_bounds__(256) void k_gemm3m(const unsigned short* __restrict__ Ain,
        const unsigned short* __restrict__ h0res, const float* __restrict__ sums,
        const float* __restrict__ gg, const float* __restrict__ beta,
        const unsigned short* __restrict__ W3t, const float* __restrict__ Wt,
        const float* __restrict__ bt,
        unsigned short* __restrict__ hmv, float* __restrict__ t_out) {
    __shared__ __align__(16) unsigned short As[64 * 128];
    __shared__ __align__(16) unsigned short Bs[64 * 128];
    __shared__ float WtS[128];
    __shared__ float prm[256];
    const int tid = threadIdx.x, lane = tid & 63, wave = tid >> 6;
    const int m0 = blockIdx.x * 64;
    if (tid < 128) {
        float mean = sums[tid] * (1.f / N_NODES);
        float var = sums[128 + tid] * (1.f / N_NODES) - mean * mean;
        float rstd = rsqrtf(var + 1e-5f);
        float sc = gg[tid] * rstd;
        prm[tid] = sc;
        prm[128 + tid] = beta[tid] - mean * sc;
        WtS[tid] = Wt[tid];
    }
    __syncthreads();
    {   // stage A: relu(bn(agg1)) + h0res
        const int ar = tid >> 2, acp = tid & 3;
        const int g = m0 + ar;
        unsigned short u[32];
        if (g < N_NODES) {
#pragma unroll
            for (int q = 0; q < 4; ++q) {
                int kb = acp * 32 + q * 8;
                float v[8], rr[8];
                unpack8(*(const uint4*)(Ain + (size_t)g * HDIM + kb), v);
                unpack8(*(const uint4*)(h0res + (size_t)g * HDIM + kb), rr);
#pragma unroll
                for (int e = 0; e < 8; ++e)
                    u[q * 8 + e] =
                        f2bf(fmaxf(v[e] * prm[kb + e] + prm[128 + kb + e], 0.f) + rr[e]);
            }
        } else {
#pragma unroll
            for (int q = 0; q < 32; ++q) u[q] = 0;
        }
#pragma unroll
        for (int q = 0; q < 4; ++q) {
            int ch = acp * 4 + q;
            int pos = ch ^ (ar & 7);
            *(uint4*)&As[ar * 128 + pos * 8] = *(const uint4*)&u[q * 8];
        }
    }
    {   // stage B (W3t [64][128]) swizzled
        const int br = tid >> 2, chq = tid & 3;
#pragma unroll
        for (int q = 0; q < 4; ++q) {
            int ch = chq * 4 + q;
            int pos = ch ^ (br & 7);
            *(uint4*)&Bs[br * 128 + pos * 8] =
                *(const uint4*)(W3t + (size_t)br * 128 + ch * 8);
        }
    }
    __syncthreads();
    const int wm = (wave >> 1) * 32, wn = (wave & 1) * 32;
    const int rl = lane & 15, kg = lane >> 4;
    f32x4 acc[2][2];
#pragma unroll
    for (int i = 0; i < 2; ++i)
#pragma unroll
        for (int j = 0; j < 2; ++j) acc[i][j] = (f32x4)0.f;
#pragma unroll
    for (int ks = 0; ks < 4; ++ks) {
        short8 a[2], b[2];
        int ch = ks * 4 + kg;
#pragma unroll
        for (int i = 0; i < 2; ++i) {
            int r = wm + i * 16 + rl;
            a[i] = *(const short8*)&As[r * 128 + (ch ^ (r & 7)) * 8];
        }
#pragma unroll
        for (int j = 0; j < 2; ++j) {
            int n = wn + j * 16 + rl;
            b[j] = *(const short8*)&Bs[n * 128 + (ch ^ (n & 7)) * 8];
        }
#pragma unroll
        for (int i = 0; i < 2; ++i)
#pragma unroll
            for (int j = 0; j < 2; ++j) acc[i][j] = mfma16(a[i], b[j], acc[i][j]);
    }
#pragma unroll
    for (int i = 0; i < 2; ++i) {
        int rb = m0 + wm + i * 16 + (lane >> 4) * 4;
#pragma unroll
        for (int j = 0; j < 2; ++j) {
            int col = wn + j * 16 + rl;
#pragma unroll
            for (int r = 0; r < 4; ++r)
                if (rb + r < N_NODES) hmv[(size_t)(rb + r) * 64 + col] = f2bf(acc[i][j][r]);
        }
    }
    {   // t-head
        const int r = wave * 16 + (lane & 15);
        const int sub = lane >> 4;
        float s = 0.f;
#pragma unroll
        for (int q = 0; q < 4; ++q) {
            int ch = sub * 4 + q;
            short8 v = *(const short8*)&As[r * 128 + (ch ^ (r & 7)) * 8];
#pragma unroll
            for (int e = 0; e < 8; ++e)
                s += bf2f((unsigned short)v[e]) * WtS[ch * 8 + e];
        }
        s += __shfl_xor(s, 16);
        s += __shfl_xor(s, 32);
        if (sub == 0 && (m0 + r) < N_NODES)
            t_out[m0 + r] = 1.f / (1.f + expf(-(s + bt[0])));
    }
}

// -------- final aggregation (64 ch, uint4, 8 lanes/row) + VAE epilogue -------
__global__ __launch_bounds__(256) void k_aggfin4(const unsigned short* __restrict__ hmv,
        const int* __restrict__ offs, const int* __restrict__ csr_src,
        const float* __restrict__ csr_w, const float* __restrict__ dinv,
        const float* __restrict__ bm, const float* __restrict__ bv,
        const float* __restrict__ eps,
        float* __restrict__ out_qz, float* __restrict__ out_qm,
        float* __restrict__ out_qs) {
    const int rg = threadIdx.x >> 3;   // 0..31 row in block
    const int lg = threadIdx.x & 7;    // channel octet
    const int row = blockIdx.x * 32 + rg;
    const int c = lg * 8;
    const bool ok = row < N_NODES;
    float a[8] = {};
    float di = 0.f;
    if (ok) {
        di = dinv[row];
        unpack8(*(const uint4*)(hmv + (size_t)row * 64 + c), a);
#pragma unroll
        for (int i = 0; i < 8; ++i) a[i] *= di;
        const int p1 = offs[row + 1];
#pragma unroll 2
        for (int p = offs[row]; p < p1; ++p) {
            int s = csr_src[p];
            float w = csr_w[p];
            float v[8];
            unpack8(*(const uint4*)(hmv + (size_t)s * 64 + c), v);
#pragma unroll
            for (int i = 0; i < 8; ++i) a[i] += w * v[i];
        }
    }
    const bool lo = lg < 4;
    float qv[8];
#pragma unroll
    for (int i = 0; i < 8; ++i)
        qv[i] = di * a[i] + (lo ? bm[c + i] : bv[c - 32 + i]);
    float sp[8] = {};
    if (!lo) {
#pragma unroll
        for (int i = 0; i < 8; ++i)
            sp[i] = fmaxf(qv[i], 0.f) + log1pf(expf(-fabsf(qv[i]))) + 1e-6f;
    }
    float spx[8];
#pragma unroll
    for (int i = 0; i < 8; ++i) spx[i] = __shfl_xor(sp[i], 4);
    if (ok) {
        if (lo) {
            *(float4*)(out_qm + (size_t)row * 32 + c) = *(const float4*)&qv[0];
            *(float4*)(out_qm + (size_t)row * 32 + c + 4) = *(const float4*)&qv[4];
            float e[8];
            *(float4*)&e[0] = *(const float4*)(eps + (size_t)row * 32 + c);
            *(float4*)&e[4] = *(const float4*)(eps + (size_t)row * 32 + c + 4);
            float qz[8];
#pragma unroll
            for (int i = 0; i < 8; ++i) qz[i] = qv[i] + spx[i] * e[i];
            *(float4*)(out_qz + (size_t)row * 32 + c) = *(const float4*)&qz[0];
            *(float4*)(out_qz + (size_t)row * 32 + c + 4) = *(const float4*)&qz[4];
        } else {
            *(float4*)(out_qs + (size_t)row * 32 + (c - 32)) = *(const float4*)&qv[0];
            *(float4*)(out_qs + (size_t)row * 32 + (c - 32) + 4) = *(const float4*)&qv[4];
        }
    }
}

extern "C" void kernel_launch(void* const* d_in, const int* in_sizes, int n_in,
                              void* d_out, int out_size, void* d_ws, size_t ws_size,
                              hipStream_t stream) {
    (void)in_sizes; (void)n_in; (void)out_size; (void)ws_size;
    const float* x   = (const float*)d_in[0];
    const int*   ei  = (const int*)d_in[1];
    const float* W1  = (const float*)d_in[2];
    const float* W2  = (const float*)d_in[4];
    const float* g1  = (const float*)d_in[6];
    const float* be1 = (const float*)d_in[7];
    const float* g2  = (const float*)d_in[8];
    const float* be2 = (const float*)d_in[9];
    const float* Wm  = (const float*)d_in[10];
    const float* bm  = (const float*)d_in[11];
    const float* Wv  = (const float*)d_in[12];
    const float* bv  = (const float*)d_in[13];
    const float* Wt  = (const float*)d_in[14];
    const float* bt  = (const float*)d_in[15];
    const float* eps = (const float*)d_in[16];

    const int* e_src = ei;
    const int* e_dst = ei + N_EDGES;

    char* ws = (char*)d_ws;
    unsigned short* HA    = (unsigned short*)(ws + OFF_HA);
    unsigned short* HB    = (unsigned short*)(ws + OFF_HB);
    unsigned short* H0RES = (unsigned short*)(ws + OFF_H0RES);
    unsigned short* HMV   = (unsigned short*)(ws + OFF_HMV);
    unsigned short* W1t   = (unsigned short*)(ws + OFF_W1T);
    unsigned short* W2t   = (unsigned short*)(ws + OFF_W2T);
    unsigned short* W3t   = (unsigned short*)(ws + OFF_W3T);
    int*   csr_src = (int*)(ws + OFF_CSRS);
    float* csr_w   = (float*)(ws + OFF_CSRW);
    int*   cnt     = (int*)(ws + OFF_CNT);
    int*   cnt2    = (int*)(ws + OFF_CNT2);
    int*   offs    = (int*)(ws + OFF_OFFS);
    float* dinv    = (float*)(ws + OFF_DINV);
    float* sumsA   = (float*)(ws + OFF_SUMSA);
    float* sumsB   = (float*)(ws + OFF_SUMSB);

    float* out_qz = (float*)d_out;
    float* out_qm = out_qz + N_NODES * ZDIM;
    float* out_qs = out_qm + N_NODES * ZDIM;
    float* out_t  = out_qs + N_NODES * ZDIM;

    const int MB = (N_NODES + 63) / 64;  // 782

    k_prep<<<1318, 256, 0, stream>>>(W1, W2, Wm, Wv, W1t, W2t, W3t,
                                     cnt, cnt2, sumsA, sumsB);
    k_count<<<(N_EDGES / 4 + 255) / 256, 256, 0, stream>>>(e_dst, cnt);
    k_scan<<<1, 1024, 0, stream>>>(cnt, offs, dinv);
    k_fill<<<(N_EDGES / 4 + 255) / 256, 256, 0, stream>>>(e_src, e_dst, offs, cnt2,
                                                          dinv, csr_src, csr_w);
    // layer 0
    k_gemm1m<<<MB, 256, 0, stream>>>(x, W1t, HA);
    k_aggs<<<MB, 256, 0, stream>>>(HA, offs, csr_src, csr_w, dinv, HB, sumsA);
    // layer 1
    k_gemm2m<<<MB, 256, 0, stream>>>(HB, W2t, sumsA, g1, be1, H0RES, HA);
    k_aggs<<<MB, 256, 0, stream>>>(HA, offs, csr_src, csr_w, dinv, HB, sumsB);
    // heads
    k_gemm3m<<<MB, 256, 0, stream>>>(HB, H0RES, sumsB, g2, be2, W3t, Wt, bt,
                                     HMV, out_t);
    k_aggfin4<<<(N_NODES + 31) / 32, 256, 0, stream>>>(HMV, offs, csr_src, csr_w,
                                                       dinv, bm, bv, eps,
                                                       out_qz, out_qm, out_qs);
}